// Round 13
// baseline (1883.308 us; speedup 1.0000x reference)
//
#include <hip/hip_runtime.h>
#include <hip/hip_cooperative_groups.h>
#include <cstddef>
#include <cstdint>

namespace cg = cooperative_groups;

#define EPS_F 1e-7f
#define MAX_NORM_F 0.99999f   // (1 - 1e-5) / SC, SC = 1
#define COOP_GRID 320

typedef __attribute__((ext_vector_type(8))) short bf16x8;  // 8 bf16 (4 VGPR)
typedef __attribute__((ext_vector_type(4))) float f32x4;

// ---------------------------------------------------------------- helpers
__device__ __forceinline__ unsigned short f2bf(float x) {
  unsigned int u = __float_as_uint(x);
  unsigned int r = u + 0x7FFFu + ((u >> 16) & 1u);   // RNE (no NaN in data)
  return (unsigned short)(r >> 16);
}
__device__ __forceinline__ float bf2f(unsigned short h) {
  return __uint_as_float(((unsigned int)h) << 16);
}

__device__ __forceinline__ float wave_sum(float v) {
#pragma unroll
  for (int off = 32; off; off >>= 1) v += __shfl_xor(v, off);
  return v;
}

__device__ __forceinline__ void store_hi4(unsigned short* H, size_t idx, float4 v) {
  ushort4 h;
  h.x = f2bf(v.x); h.y = f2bf(v.y); h.z = f2bf(v.z); h.w = f2bf(v.w);
  *reinterpret_cast<ushort4*>(H + idx) = h;
}

// async global->LDS, 16B per lane; LDS dest = uniform base + lane*16
__device__ __forceinline__ void gl_lds16(const unsigned short* g, unsigned short* l) {
  __builtin_amdgcn_global_load_lds(
      (const __attribute__((address_space(1))) void*)g,
      (__attribute__((address_space(3))) void*)l, 16, 0, 0);
}

// fragment read offset (elements) for logical row r, k-group kg, tile base tb
__device__ __forceinline__ int frag_off(int tb, int r, int kg) {
  return tb + r * 32 + ((kg ^ ((r >> 1) & 3)) << 3);
}

// ------------------------------- A fp32 -> bf16 pre-pass (stacked, padded)
__global__ __launch_bounds__(256) void c2bf_k(
    const float* __restrict__ A0, const float* __restrict__ A1,
    const float* __restrict__ A2, const float* __restrict__ A3,
    unsigned short* __restrict__ Abf)
{
  const int row = blockIdx.x * 4 + (threadIdx.x >> 6);   // 0..61439
  const int lane = threadIdx.x & 63;
  const int c = row / 15360;
  const int lr = row - c * 15360;
  const float* A = (c == 0) ? A0 : (c == 1) ? A1 : (c == 2) ? A2 : A3;

  float4 f0 = make_float4(0.f, 0.f, 0.f, 0.f), f1 = f0;
  if (lane < 63) {
    const float* p = A + (size_t)lr * 504 + lane * 8;
    f0 = *reinterpret_cast<const float4*>(p);
    f1 = *reinterpret_cast<const float4*>(p + 4);
  }
  bf16x8 o;
  o[0] = (short)f2bf(f0.x); o[1] = (short)f2bf(f0.y);
  o[2] = (short)f2bf(f0.z); o[3] = (short)f2bf(f0.w);
  o[4] = (short)f2bf(f1.x); o[5] = (short)f2bf(f1.y);
  o[6] = (short)f2bf(f1.z); o[7] = (short)f2bf(f1.w);
  *reinterpret_cast<bf16x8*>(Abf + (size_t)row * 512 + lane * 8) = o;
}

// --------------------------------------------- weight transpose+split pass
struct WS8 {
  const float* W[8];
  unsigned short* Th[8];
  unsigned short* Tl[8];
  int K[8], N[8], Kp[8];
};

__global__ __launch_bounds__(256) void wsplit_all_k(WS8 d) {
  const int zi = blockIdx.z;
  const float* W = d.W[zi];
  unsigned short* Th = d.Th[zi];
  unsigned short* Tl = d.Tl[zi];
  const int K = d.K[zi], N = d.N[zi], Kp = d.Kp[zi];
  const int n0 = blockIdx.x * 64, k0 = blockIdx.y * 64;
  if (n0 >= N || k0 >= Kp) return;

  __shared__ float T[64][65];
  const int t = threadIdx.x;
  {
    const int lk = t >> 2;
    const int ln = (t & 3) * 16;
    const int gk = k0 + lk;
#pragma unroll
    for (int j = 0; j < 16; j += 4) {
      float4 v = make_float4(0.f, 0.f, 0.f, 0.f);
      const int gn = n0 + ln + j;
      if (gk < K) {
        if (gn + 3 < N) {
          v = *reinterpret_cast<const float4*>(W + (size_t)gk * N + gn);
        } else {
          const float* p = W + (size_t)gk * N;
          if (gn     < N) v.x = p[gn];
          if (gn + 1 < N) v.y = p[gn + 1];
          if (gn + 2 < N) v.z = p[gn + 2];
          if (gn + 3 < N) v.w = p[gn + 3];
        }
      }
      T[lk][ln + j + 0] = v.x; T[lk][ln + j + 1] = v.y;
      T[lk][ln + j + 2] = v.z; T[lk][ln + j + 3] = v.w;
    }
  }
  __syncthreads();
  {
    const int rn = t >> 2;
    const int rk = (t & 3) * 16;
    const int gn = n0 + rn;
    if (gn < N) {
      size_t base = (size_t)gn * Kp + k0 + rk;
#pragma unroll
      for (int j = 0; j < 16; ++j) {
        float x = T[rk + j][rn];
        unsigned short h = f2bf(x);
        unsigned short l = f2bf(x - bf2f(h));
        Th[base + j] = h;
        Tl[base + j] = l;
      }
    }
  }
}

// ---------------------------- 128x64 x1 GEMM core (device fn, 24KB LDS dbuf)
__device__ void gemm_dev(
    unsigned short* sm,
    const unsigned short* Ah, int lda,
    const unsigned short* Bh, int ldb,
    const float* bias, float* Cf, unsigned short* Ch,
    int ldc, int N, int koff, int klen, int relu, int bm, int bn)
{
  const int t = threadIdx.x;
  const int lane = t & 63, wave = t >> 6;
  const int wm = (wave >> 1) * 64, wn = (wave & 1) * 32;
  const int fr = lane & 15, kg = lane >> 4;

  const unsigned short* sp[3];
  int dpo[3];
#pragma unroll
  for (int q = 0; q < 3; ++q) {
    const int j = wave + 4 * q;
    int tile, i;
    if (j < 8) { tile = 0; i = j; }
    else       { tile = 1; i = j - 8; }
    const int row = i * 16 + (lane >> 2);
    const int chunk = (lane & 3) ^ ((row >> 1) & 3);
    const unsigned short* base = (tile == 0) ? Ah : Bh;
    const int ld = (tile == 0) ? lda : ldb;
    const int grow = (tile == 0) ? (bm + row) : min(bn + row, N - 1);
    const int tb = (tile == 0) ? 0 : 4096;
    sp[q] = base + (size_t)grow * ld + koff + chunk * 8;
    dpo[q] = tb + i * 512 + lane * 8;
  }

  int offA[4], offB[2];
#pragma unroll
  for (int i = 0; i < 4; ++i) offA[i] = frag_off(0, wm + i * 16 + fr, kg);
#pragma unroll
  for (int i = 0; i < 2; ++i) offB[i] = frag_off(4096, wn + i * 16 + fr, kg);

  f32x4 acc[4][2] = {};
#pragma unroll
  for (int q = 0; q < 3; ++q) gl_lds16(sp[q], sm + dpo[q]);

  int cur = 0;
  for (int k0 = 0; k0 < klen; k0 += 32) {
    __syncthreads();                     // buf[cur] staged
    if (k0 + 32 < klen) {
      unsigned short* nb = sm + (cur ^ 1) * 6144;
#pragma unroll
      for (int q = 0; q < 3; ++q) { sp[q] += 32; gl_lds16(sp[q], nb + dpo[q]); }
    }
    const unsigned short* s = sm + cur * 6144;
    bf16x8 ah[4], bh[2];
#pragma unroll
    for (int i = 0; i < 4; ++i)
      ah[i] = *reinterpret_cast<const bf16x8*>(s + offA[i]);
#pragma unroll
    for (int i = 0; i < 2; ++i)
      bh[i] = *reinterpret_cast<const bf16x8*>(s + offB[i]);
#pragma unroll
    for (int mi = 0; mi < 4; ++mi)
#pragma unroll
      for (int ni = 0; ni < 2; ++ni)
        acc[mi][ni] = __builtin_amdgcn_mfma_f32_16x16x32_bf16(ah[mi], bh[ni], acc[mi][ni], 0, 0, 0);
    cur ^= 1;
  }

#pragma unroll
  for (int mi = 0; mi < 4; ++mi) {
#pragma unroll
    for (int ni = 0; ni < 2; ++ni) {
      const int col = bn + wn + ni * 16 + fr;
      if (col >= N) continue;
      const int row0 = bm + wm + mi * 16 + kg * 4;
      const float bv = bias ? bias[col] : 0.f;
      if (Cf) {
#pragma unroll
        for (int r = 0; r < 4; ++r) {
          float v = acc[mi][ni][r] + bv;
          if (relu) v = fmaxf(v, 0.f);
          Cf[(size_t)(row0 + r) * ldc + col] = v;
        }
      } else {
#pragma unroll
        for (int r = 0; r < 4; ++r) {
          float v = acc[mi][ni][r] + bv;
          if (relu) v = fmaxf(v, 0.f);
          Ch[(size_t)(row0 + r) * ldc + col] = f2bf(v);
        }
      }
    }
  }
}

// ------------------------------------------ standalone x1 GEMM (fallback+C)
__global__ __launch_bounds__(256) void gemm_n64_x1(
    const unsigned short* __restrict__ Ah, int lda,
    const unsigned short* __restrict__ Bh, int ldb,
    const float* __restrict__ bias, float* __restrict__ Cf,
    unsigned short* __restrict__ Ch,
    int ldc, int M, int N, int Ktot, int kslice, int relu)
{
  __shared__ unsigned short sm[12288];
  const int z = blockIdx.z;
  const int koff = z * kslice;
  const int klen = min(kslice, Ktot - koff);
  float* Cz = Cf ? (Cf + (size_t)z * (size_t)M * (size_t)N) : nullptr;
  gemm_dev(sm, Ah, lda, Bh, ldb, bias, Cz, Ch, ldc, N, koff, klen, relu,
           blockIdx.x * 128, blockIdx.y * 64);
}

// ---- embed GEMM: x1 (Ah*Bh), all-bf16, all-gl_lds, 128x128 tile,
// dbuf 32KB LDS, 1 barrier/iter. A = Abf[61440][512]; TAN bf16-hi out.
__global__ __launch_bounds__(256) void gemm_embed1(
    const unsigned short* __restrict__ Abf, const unsigned short* __restrict__ EW,
    const float* __restrict__ b_embed, unsigned short* __restrict__ TAN)
{
  __shared__ unsigned short sm[16384];   // 2 x (Ah@0 Bh@4096)

  const int t = threadIdx.x;
  const int bx = blockIdx.x;
  const int bm = bx * 128;               // global row into Abf/TAN
  const int bn = blockIdx.y * 128;       // 0 or 128
  const int c  = bx / 120;
  const unsigned short* Bh = EW + (size_t)c * 262144u;
  const float* bias = b_embed + c * 256;

  const int lane = t & 63, wave = t >> 6;
  const int wm = (wave >> 1) * 64, wn = (wave & 1) * 64;
  const int fr = lane & 15, kg = lane >> 4;

  const unsigned short* sp[4];
  int dpo[4];
#pragma unroll
  for (int q = 0; q < 4; ++q) {
    const int j = wave + 4 * q;
    const int tile = j >> 3;
    const int i = j & 7;
    const int row = i * 16 + (lane >> 2);
    const int chunk = (lane & 3) ^ ((row >> 1) & 3);
    const unsigned short* base = (tile == 0) ? Abf : Bh;
    const int grow = (tile == 0) ? (bm + row) : (bn + row);
    const int tb = tile * 4096;
    sp[q] = base + (size_t)grow * 512 + chunk * 8;
    dpo[q] = tb + i * 512 + lane * 8;
  }

  int offA[4], offB[4];
#pragma unroll
  for (int i = 0; i < 4; ++i) {
    offA[i] = frag_off(0,    wm + i * 16 + fr, kg);
    offB[i] = frag_off(4096, wn + i * 16 + fr, kg);
  }

  f32x4 acc[4][4] = {};
#pragma unroll
  for (int q = 0; q < 4; ++q) gl_lds16(sp[q], sm + dpo[q]);

  int cur = 0;
  for (int k0 = 0; k0 < 512; k0 += 32) {
    __syncthreads();                     // buf[cur] staged (vmcnt drained)
    if (k0 + 32 < 512) {
      unsigned short* nb = sm + (cur ^ 1) * 8192;
#pragma unroll
      for (int q = 0; q < 4; ++q) { sp[q] += 32; gl_lds16(sp[q], nb + dpo[q]); }
    }
    const unsigned short* s = sm + cur * 8192;
    bf16x8 ah[4], bh[4];
#pragma unroll
    for (int i = 0; i < 4; ++i) {
      ah[i] = *reinterpret_cast<const bf16x8*>(s + offA[i]);
      bh[i] = *reinterpret_cast<const bf16x8*>(s + offB[i]);
    }
#pragma unroll
    for (int mi = 0; mi < 4; ++mi)
#pragma unroll
      for (int ni = 0; ni < 4; ++ni)
        acc[mi][ni] = __builtin_amdgcn_mfma_f32_16x16x32_bf16(ah[mi], bh[ni], acc[mi][ni], 0, 0, 0);
    cur ^= 1;
  }

#pragma unroll
  for (int mi = 0; mi < 4; ++mi) {
#pragma unroll
    for (int ni = 0; ni < 4; ++ni) {
      const int col = bn + wn + ni * 16 + fr;
      const int row0 = bm + wm + mi * 16 + kg * 4;
      const float bv = bias[col];
#pragma unroll
      for (int r = 0; r < 4; ++r)
        TAN[(size_t)(row0 + r) * 256 + col] = f2bf(acc[mi][ni][r] + bv);
    }
  }
}

// ------------------------------------------------ device bodies (shared)
__device__ __forceinline__ void ln_row_body(
    const unsigned short* TAN, const float* gamma, const float* beta,
    float* Z, int row, int lane)
{
  const int b = row / 30;
  const int n = row % 30;
  float4 tc[4];
  float4 ts = make_float4(0.f, 0.f, 0.f, 0.f);
#pragma unroll
  for (int c = 0; c < 4; ++c) {
    ushort4 xu = *reinterpret_cast<const ushort4*>(
        TAN + ((size_t)c * 15360 + row) * 256 + lane * 4);
    float4 x = make_float4(bf2f(xu.x), bf2f(xu.y), bf2f(xu.z), bf2f(xu.w));
    float mu = wave_sum(x.x + x.y + x.z + x.w) * (1.f / 256.f);
    float4 xm = make_float4(x.x - mu, x.y - mu, x.z - mu, x.w - mu);
    float var = wave_sum(xm.x * xm.x + xm.y * xm.y + xm.z * xm.z + xm.w * xm.w)
                * (1.f / 256.f);
    float rs = rsqrtf(var + 1e-5f);
    float4 g = *reinterpret_cast<const float4*>(gamma + c * 256 + lane * 4);
    float4 be = *reinterpret_cast<const float4*>(beta + c * 256 + lane * 4);
    float4 tv = make_float4(xm.x * rs * g.x + be.x, xm.y * rs * g.y + be.y,
                            xm.z * rs * g.z + be.z, xm.w * rs * g.w + be.w);
    tc[c] = tv;
    ts.x += tv.x; ts.y += tv.y; ts.z += tv.z; ts.w += tv.w;
  }
#pragma unroll
  for (int g5 = 0; g5 < 5; ++g5) {
    float4 v = (g5 == 0) ? ts : tc[g5 - 1];
    float n2 = wave_sum(v.x * v.x + v.y * v.y + v.z * v.z + v.w * v.w);
    float nn = fmaxf(sqrtf(n2), EPS_F);
    float th = tanhf(nn);
    float w = th / nn;
    if (th > MAX_NORM_F) w *= MAX_NORM_F / fmaxf(th, EPS_F);
    float4 o = make_float4(v.x * w, v.y * w, v.z * w, v.w * w);
    *reinterpret_cast<float4*>(
        Z + (((size_t)g5 * 512 + b) * 38 + n) * 256 + lane * 4) = o;
  }
}

__device__ __forceinline__ float4 pair_log(const float* zr, int c, int lane) {
  float4 x = *reinterpret_cast<const float4*>(zr + (size_t)c * 256 + lane * 4);
  float4 y = *reinterpret_cast<const float4*>(zr + (size_t)(c + 1) * 256 + lane * 4);
  float x2 = wave_sum(x.x * x.x + x.y * x.y + x.z * x.z + x.w * x.w);
  float y2 = wave_sum(y.x * y.x + y.y * y.y + y.z * y.z + y.w * y.w);
  float xy = wave_sum(x.x * y.x + x.y * y.y + x.z * y.z + x.w * y.w);
  float a  = 1.f - 2.f * xy + y2;
  float bb = 1.f - x2;
  float den = fmaxf(1.f - 2.f * xy + x2 * y2, EPS_F);
  float inv = 1.f / den;
  float4 u;
  u.x = (bb * y.x - a * x.x) * inv;
  u.y = (bb * y.y - a * x.y) * inv;
  u.z = (bb * y.z - a * x.z) * inv;
  u.w = (bb * y.w - a * x.w) * inv;
  float u2 = wave_sum(u.x * u.x + u.y * u.y + u.z * u.z + u.w * u.w);
  float un = fmaxf(sqrtf(u2), EPS_F);
  float coef = fmaxf(1.f - x2, EPS_F) * atanhf(fminf(un, 1.f - 1e-7f)) / un;
  float4 o;
  o.x = coef * u.x; o.y = coef * u.y; o.z = coef * u.z; o.w = coef * u.w;
  return o;
}

__device__ __forceinline__ float4 logmap0_col(const float* zr, int c, int lane) {
  float4 z = *reinterpret_cast<const float4*>(zr + (size_t)c * 256 + lane * 4);
  float z2 = wave_sum(z.x * z.x + z.y * z.y + z.z * z.z + z.w * z.w);
  float nz = fmaxf(sqrtf(z2), EPS_F);
  float cc = atanhf(fminf(nz, 1.f - 1e-7f)) / nz;
  float4 o;
  o.x = cc * z.x; o.y = cc * z.y; o.z = cc * z.z; o.w = cc * z.w;
  return o;
}

// vel0 body for one row (4-wave split; red = float[4][256] in LDS)
__device__ __forceinline__ void vel0_body(
    const float* Z, unsigned short* Fh, float* VSUM, float* red,
    int r, int wave, int lane)
{
  const float* zr = Z + (size_t)r * 38 * 256;
  float4 vs = make_float4(0.f, 0.f, 0.f, 0.f);
  for (int j = wave; j < 29; j += 4) {
    float4 p = pair_log(zr, j, lane);
    vs.x += p.x; vs.y += p.y; vs.z += p.z; vs.w += p.w;
  }
  *reinterpret_cast<float4*>(red + wave * 256 + lane * 4) = vs;
  __syncthreads();

  const size_t fb = (size_t)r * 768 + lane * 4;
  if (wave == 0) {
    float4 a0 = *reinterpret_cast<const float4*>(red + 0 * 256 + lane * 4);
    float4 a1 = *reinterpret_cast<const float4*>(red + 1 * 256 + lane * 4);
    float4 a2 = *reinterpret_cast<const float4*>(red + 2 * 256 + lane * 4);
    float4 a3 = *reinterpret_cast<const float4*>(red + 3 * 256 + lane * 4);
    vs.x = a0.x + a1.x + a2.x + a3.x;
    vs.y = a0.y + a1.y + a2.y + a3.y;
    vs.z = a0.z + a1.z + a2.z + a3.z;
    vs.w = a0.w + a1.w + a2.w + a3.w;
    *reinterpret_cast<float4*>(VSUM + (size_t)r * 256 + lane * 4) = vs;
    const float s29 = 1.f / 29.f;
    float4 o;
    o.x = vs.x * s29; o.y = vs.y * s29; o.z = vs.z * s29; o.w = vs.w * s29;
    store_hi4(Fh, fb + 512, o);
  } else if (wave == 1) {
    float4 fl = logmap0_col(zr, 29, lane);
    store_hi4(Fh, fb, fl);
  } else if (wave == 2) {
    float4 fp = logmap0_col(zr, 28, lane);
    store_hi4(Fh, fb + 256, fp);
  }
  __syncthreads();   // protect red for next iteration
}

// expmap body: 2 waves per row (role 0 main, role 1 helper); pmL float[2][256]
__device__ __forceinline__ void expmap_body(
    float* Z, const float* VP, const float* b3, unsigned short* Fh,
    float* VSUM, float* pmL, int r, int rloc, int role, int lane, int t)
{
  float* zr = Z + (size_t)r * 38 * 256;
  const size_t fb = (size_t)r * 768 + lane * 4;

  float4 res, u;
  float coef = 0.f, rn = 0.f, x2 = 0.f;

  if (role == 0) {
    float4 x = *reinterpret_cast<const float4*>(zr + (size_t)(t + 29) * 256 + lane * 4);
    float4 v = *reinterpret_cast<const float4*>(b3 + lane * 4);
#pragma unroll
    for (int p = 0; p < 4; ++p) {
      float4 a = *reinterpret_cast<const float4*>(
          VP + (size_t)p * 655360u + (size_t)r * 256 + lane * 4);
      v.x += a.x; v.y += a.y; v.z += a.z; v.w += a.w;
    }
    x2 = wave_sum(x.x * x.x + x.y * x.y + x.z * x.z + x.w * x.w);
    float v2 = wave_sum(v.x * v.x + v.y * v.y + v.z * v.z + v.w * v.w);
    float xv = wave_sum(x.x * v.x + x.y * v.y + x.z * v.z + x.w * v.w);

    float vn = fmaxf(sqrtf(v2), EPS_F);
    float lamx = 2.f / fmaxf(1.f - x2, EPS_F);
    float s = tanhf(0.5f * lamx * vn) / vn;
    float xy = s * xv;
    float y2 = s * s * v2;
    float a  = 1.f + 2.f * xy + y2;
    float bb = 1.f - x2;
    float den = fmaxf(1.f + 2.f * xy + x2 * y2, EPS_F);
    float inv = 1.f / den;
    res.x = (a * x.x + bb * s * v.x) * inv;
    res.y = (a * x.y + bb * s * v.y) * inv;
    res.z = (a * x.z + bb * s * v.z) * inv;
    res.w = (a * x.w + bb * s * v.w) * inv;
    float r2 = wave_sum(res.x * res.x + res.y * res.y + res.z * res.z + res.w * res.w);
    rn = sqrtf(r2);
    if (rn > MAX_NORM_F) {
      float sc = MAX_NORM_F / fmaxf(rn, EPS_F);
      res.x *= sc; res.y *= sc; res.z *= sc; res.w *= sc;
      r2 = MAX_NORM_F * MAX_NORM_F;
      rn = MAX_NORM_F;
    }
    *reinterpret_cast<float4*>(zr + (size_t)(t + 30) * 256 + lane * 4) = res;

    if (t < 7) {
      float xyn = wave_sum(x.x * res.x + x.y * res.y + x.z * res.z + x.w * res.w);
      float an  = 1.f - 2.f * xyn + r2;
      float bbn = 1.f - x2;
      float denn = fmaxf(1.f - 2.f * xyn + x2 * r2, EPS_F);
      float invn = 1.f / denn;
      u.x = (bbn * res.x - an * x.x) * invn;
      u.y = (bbn * res.y - an * x.y) * invn;
      u.z = (bbn * res.z - an * x.z) * invn;
      u.w = (bbn * res.w - an * x.w) * invn;
      float u2 = wave_sum(u.x * u.x + u.y * u.y + u.z * u.z + u.w * u.w);
      float un = fmaxf(sqrtf(u2), EPS_F);
      coef = fmaxf(1.f - x2, EPS_F) * atanhf(fminf(un, 1.f - 1e-7f)) / un;
    }
  } else if (t < 7) {
    float4 pm = pair_log(zr, t, lane);
    *reinterpret_cast<float4*>(pmL + rloc * 256 + lane * 4) = pm;
    float4 x = *reinterpret_cast<const float4*>(zr + (size_t)(t + 29) * 256 + lane * 4);
    float hx2 = wave_sum(x.x * x.x + x.y * x.y + x.z * x.z + x.w * x.w);
    float nx = fmaxf(sqrtf(hx2), EPS_F);
    float cp = atanhf(fminf(nx, 1.f - 1e-7f)) / nx;
    float4 o;
    o.x = cp * x.x; o.y = cp * x.y; o.z = cp * x.z; o.w = cp * x.w;
    store_hi4(Fh, fb + 256, o);
  }

  __syncthreads();

  if (role == 0 && t < 7) {
    float4 pm = *reinterpret_cast<const float4*>(pmL + rloc * 256 + lane * 4);
    float4 vs = *reinterpret_cast<const float4*>(VSUM + (size_t)r * 256 + lane * 4);
    vs.x += coef * u.x - pm.x; vs.y += coef * u.y - pm.y;
    vs.z += coef * u.z - pm.z; vs.w += coef * u.w - pm.w;
    *reinterpret_cast<float4*>(VSUM + (size_t)r * 256 + lane * 4) = vs;

    float rnp = fmaxf(rn, EPS_F);
    float cl = atanhf(fminf(rnp, 1.f - 1e-7f)) / rnp;
    float4 o;
    o.x = cl * res.x; o.y = cl * res.y; o.z = cl * res.z; o.w = cl * res.w;
    store_hi4(Fh, fb, o);
    const float s29 = 1.f / 29.f;
    o.x = vs.x * s29; o.y = vs.y * s29; o.z = vs.z * s29; o.w = vs.w * s29;
    store_hi4(Fh, fb + 512, o);
  }
  __syncthreads();   // protect pmL for next iteration
}

// --------------------- standalone kernels for fallback path
__global__ __launch_bounds__(256) void ln_expmap0_k(
    const unsigned short* __restrict__ TAN, const float* __restrict__ gamma,
    const float* __restrict__ beta, float* __restrict__ Z)
{
  ln_row_body(TAN, gamma, beta, Z, blockIdx.x * 4 + (threadIdx.x >> 6),
              threadIdx.x & 63);
}

__global__ __launch_bounds__(256) void vel_feat_t0_k(
    const float* __restrict__ Z, unsigned short* __restrict__ Fh,
    float* __restrict__ VSUM)
{
  __shared__ float red[4 * 256];
  vel0_body(Z, Fh, VSUM, red, blockIdx.x, threadIdx.x >> 6, threadIdx.x & 63);
}

__global__ __launch_bounds__(256) void expmap_vel_fused_k(
    float* __restrict__ Z, const float* __restrict__ VP,
    const float* __restrict__ b3, unsigned short* __restrict__ Fh,
    float* __restrict__ VSUM, int t)
{
  __shared__ float pmL[2 * 256];
  const int wave = threadIdx.x >> 6, lane = threadIdx.x & 63;
  const int rloc = wave >> 1, role = wave & 1;
  expmap_body(Z, VP, b3, Fh, VSUM, pmL, blockIdx.x * 2 + rloc, rloc, role, lane, t);
}

__global__ __launch_bounds__(256) void logmap0_rows_k(
    const float* __restrict__ Z, unsigned short* __restrict__ Uh)
{
  const int q = blockIdx.x * 4 + (threadIdx.x >> 6);
  const int lane = threadIdx.x & 63;
  const int r = q >> 3;
  const int tt = q & 7;
  float4 o = logmap0_col(Z + (size_t)r * 38 * 256, 30 + tt, lane);
  store_hi4(Uh, (size_t)q * 256 + lane * 4, o);
}

// ---------------------------- cooperative mega-kernel: LN, vel0, 8 steps
struct CoopArgs {
  const unsigned short* TAN;
  const float* ln_g; const float* ln_b;
  float* Z;
  unsigned short* FEATh; float* VSUM;
  unsigned short* H1h; unsigned short* H2h;
  const unsigned short* W1h; const unsigned short* W2h; const unsigned short* W3h;
  const float* b1; const float* b2; const float* b3;
  float* VP;
};

__global__ __launch_bounds__(256, 2) void coop_steps_k(CoopArgs a) {
  __shared__ unsigned short sm[12288];   // 24KB: gemm dbuf / red / pmL union
  cg::grid_group grid = cg::this_grid();
  const int bid = blockIdx.x;
  const int wave = threadIdx.x >> 6, lane = threadIdx.x & 63;

  // Phase LN: 3840 row-groups of 4 rows
  for (int rb = bid; rb < 3840; rb += COOP_GRID)
    ln_row_body(a.TAN, a.ln_g, a.ln_b, a.Z, rb * 4 + wave, lane);
  grid.sync();

  // Phase vel0: 2560 rows
  {
    float* red = (float*)sm;
    for (int r = bid; r < 2560; r += COOP_GRID)
      vel0_body(a.Z, a.FEATh, a.VSUM, red, r, wave, lane);
  }
  grid.sync();

  for (int t = 0; t < 8; ++t) {
    {  // W1: FEAT[2560][768] x W1h -> H1h, relu. tiles 20x16 = 320
      const int bm = (bid % 20) * 128, bn = (bid / 20) * 64;
      gemm_dev(sm, a.FEATh, 768, a.W1h, 768, a.b1, nullptr, a.H1h,
               1024, 1024, 0, 768, 1, bm, bn);
    }
    grid.sync();
    {  // W2: H1h x W2h -> H2h, relu
      const int bm = (bid % 20) * 128, bn = (bid / 20) * 64;
      gemm_dev(sm, a.H1h, 1024, a.W2h, 1024, a.b2, nullptr, a.H2h,
               1024, 1024, 0, 1024, 1, bm, bn);
    }
    grid.sync();
    {  // W3: H2h x W3h -> VP (split-K 4). 20 x 4 x 4 = 320
      const int q = bid % 80;
      const int z = bid / 80;
      const int bm = (q % 20) * 128, bn = (q / 20) * 64;
      gemm_dev(sm, a.H2h, 1024, a.W3h, 1024, nullptr,
               a.VP + (size_t)z * 655360u, nullptr,
               256, 256, z * 256, 256, 0, bm, bn);
    }
    grid.sync();
    {  // expmap: 1280 row-pairs (2 waves/row)
      float* pmL = (float*)sm;
      const int rloc = wave >> 1, role = wave & 1;
      for (int rp = bid; rp < 1280; rp += COOP_GRID)
        expmap_body(a.Z, a.VP, a.b3, a.FEATh, a.VSUM, pmL,
                    rp * 2 + rloc, rloc, role, lane, t);
    }
    grid.sync();
  }
}

// ---------------------------------------------------------------- launcher
extern "C" void kernel_launch(void* const* d_in, const int* in_sizes, int n_in,
                              void* d_out, int out_size, void* d_ws, size_t ws_size,
                              hipStream_t stream)
{
  const float* c0 = (const float*)d_in[0];
  const float* c1 = (const float*)d_in[1];
  const float* c2 = (const float*)d_in[2];
  const float* c3 = (const float*)d_in[3];
  const float* W_embed = (const float*)d_in[4];
  const float* b_embed = (const float*)d_in[5];
  const float* ln_g    = (const float*)d_in[6];
  const float* ln_b    = (const float*)d_in[7];
  const float* W1 = (const float*)d_in[8];
  const float* b1 = (const float*)d_in[9];
  const float* W2 = (const float*)d_in[10];
  const float* b2 = (const float*)d_in[11];
  const float* W3 = (const float*)d_in[12];
  const float* b3 = (const float*)d_in[13];
  const float* W_out = (const float*)d_in[14];
  const float* b_out = (const float*)d_in[15];
  float* out = (float*)d_out;
  float* ws  = (float*)d_ws;

  // ---- ws layout (proven footprint).
  float* Z = ws;
  unsigned short* Abf = (unsigned short*)ws;        // aliases Z (stage A only)
  unsigned short* Rs = (unsigned short*)(ws + 24903680u);
  unsigned short* TAN = Rs + 20000000u;             // 4*15360*256 shorts
  unsigned short* W1h = Rs;                         // [1024][768]
  unsigned short* W1l = Rs + 786432u;
  unsigned short* W2h = Rs + 1572864u;              // [1024][1024]
  unsigned short* W2l = Rs + 2621440u;
  unsigned short* W3h = Rs + 3670016u;              // [256][1024]
  unsigned short* W3l = Rs + 3932160u;
  unsigned short* Woh = Rs + 4194304u;              // [504][256]
  unsigned short* Wol = Rs + 4323328u;
  unsigned short* FEATh = Rs + 4452352u;            // [2560][768]
  unsigned short* H1h = Rs + 6418432u;              // [2560][1024]
  unsigned short* H2h = Rs + 9039872u;              // [2560][1024]
  unsigned short* Uh  = Rs + 11661312u;             // [20480][256] (stage C)
  float* VP   = ws + 34338816u;                     // 4 x 2560*256 parts
  float* VSUM = ws + 39581696u;                     // 2560*256

  unsigned short* EW = (unsigned short*)d_out;      // embed weights scratch

  dim3 blk(256);

  // Stage A: A->bf16 pre-pass + all 8 weight splits -> embed GEMM
  c2bf_k<<<dim3(15360), blk, 0, stream>>>(c0, c1, c2, c3, Abf);
  {
    WS8 d;
    for (int c = 0; c < 4; ++c) {
      d.W[c] = W_embed + (size_t)c * 504 * 256;
      d.Th[c] = EW + (size_t)c * 262144u;
      d.Tl[c] = EW + (size_t)c * 262144u + 131072u;
      d.K[c] = 504; d.N[c] = 256; d.Kp[c] = 512;
    }
    d.W[4] = W1;    d.Th[4] = W1h; d.Tl[4] = W1l; d.K[4] = 768;  d.N[4] = 1024; d.Kp[4] = 768;
    d.W[5] = W2;    d.Th[5] = W2h; d.Tl[5] = W2l; d.K[5] = 1024; d.N[5] = 1024; d.Kp[5] = 1024;
    d.W[6] = W3;    d.Th[6] = W3h; d.Tl[6] = W3l; d.K[6] = 1024; d.N[6] = 256;  d.Kp[6] = 1024;
    d.W[7] = W_out; d.Th[7] = Woh; d.Tl[7] = Wol; d.K[7] = 256;  d.N[7] = 504;  d.Kp[7] = 256;
    wsplit_all_k<<<dim3(16, 16, 8), blk, 0, stream>>>(d);
  }
  gemm_embed1<<<dim3(480, 2), blk, 0, stream>>>(Abf, EW, b_embed, TAN);

  // Stage B: LN + vel0 + 8 steps — cooperative mega-kernel (w/ fallback)
  bool coopDone = false;
  {
    int dev = 0;
    (void)hipGetDevice(&dev);
    int coopOK = 0, numCU = 0, maxB = 0;
    (void)hipDeviceGetAttribute(&coopOK, hipDeviceAttributeCooperativeLaunch, dev);
    (void)hipDeviceGetAttribute(&numCU, hipDeviceAttributeMultiprocessorCount, dev);
    (void)hipOccupancyMaxActiveBlocksPerMultiprocessor(&maxB, coop_steps_k, 256, 0);
    if (coopOK && (long)maxB * numCU >= COOP_GRID) {
      CoopArgs ca;
      ca.TAN = TAN; ca.ln_g = ln_g; ca.ln_b = ln_b; ca.Z = Z;
      ca.FEATh = FEATh; ca.VSUM = VSUM; ca.H1h = H1h; ca.H2h = H2h;
      ca.W1h = W1h; ca.W2h = W2h; ca.W3h = W3h;
      ca.b1 = b1; ca.b2 = b2; ca.b3 = b3; ca.VP = VP;
      void* kp[] = {(void*)&ca};
      hipError_t ce = hipLaunchCooperativeKernel(
          coop_steps_k, dim3(COOP_GRID), dim3(256), kp, 0, stream);
      coopDone = (ce == hipSuccess);
    }
  }
  if (!coopDone) {
    ln_expmap0_k<<<dim3(3840), blk, 0, stream>>>(TAN, ln_g, ln_b, Z);
    vel_feat_t0_k<<<dim3(2560), blk, 0, stream>>>(Z, FEATh, VSUM);
    for (int t = 0; t < 8; ++t) {
      gemm_n64_x1<<<dim3(20, 16, 1), blk, 0, stream>>>(
          FEATh, 768, W1h, 768, b1, nullptr, H1h,
          1024, 2560, 1024, 768, 768, 1);
      gemm_n64_x1<<<dim3(20, 16, 1), blk, 0, stream>>>(
          H1h, 1024, W2h, 1024, b2, nullptr, H2h,
          1024, 2560, 1024, 1024, 1024, 1);
      gemm_n64_x1<<<dim3(20, 4, 4), blk, 0, stream>>>(
          H2h, 1024, W3h, 1024, nullptr, VP, nullptr,
          256, 2560, 256, 1024, 256, 0);
      expmap_vel_fused_k<<<dim3(1280), blk, 0, stream>>>(
          Z, VP, b3, FEATh, VSUM, t);
    }
  }

  // Stage C: logmap0 -> final projection into d_out (x1)
  logmap0_rows_k<<<dim3(5120), blk, 0, stream>>>(Z, Uh);
  gemm_n64_x1<<<dim3(160, 8, 1), blk, 0, stream>>>(
      Uh, 256, Woh, 256, b_out, out, nullptr,
      504, 20480, 504, 256, 256, 0);
}

// Round 14
// 564.223 us; speedup vs baseline: 3.3379x; 3.3379x over previous
//
#include <hip/hip_runtime.h>
#include <cstddef>
#include <cstdint>

#define EPS_F 1e-7f
#define MAX_NORM_F 0.99999f   // (1 - 1e-5) / SC, SC = 1

typedef __attribute__((ext_vector_type(8))) short bf16x8;  // 8 bf16 (4 VGPR)
typedef __attribute__((ext_vector_type(4))) float f32x4;

// ---------------------------------------------------------------- helpers
__device__ __forceinline__ unsigned short f2bf(float x) {
  unsigned int u = __float_as_uint(x);
  unsigned int r = u + 0x7FFFu + ((u >> 16) & 1u);   // RNE (no NaN in data)
  return (unsigned short)(r >> 16);
}
__device__ __forceinline__ float bf2f(unsigned short h) {
  return __uint_as_float(((unsigned int)h) << 16);
}

__device__ __forceinline__ float wave_sum(float v) {
#pragma unroll
  for (int off = 32; off; off >>= 1) v += __shfl_xor(v, off);
  return v;
}

__device__ __forceinline__ void store_hi4(unsigned short* H, size_t idx, float4 v) {
  ushort4 h;
  h.x = f2bf(v.x); h.y = f2bf(v.y); h.z = f2bf(v.z); h.w = f2bf(v.w);
  *reinterpret_cast<ushort4*>(H + idx) = h;
}

// async global->LDS, 16B per lane; LDS dest = uniform base + lane*16
__device__ __forceinline__ void gl_lds16(const unsigned short* g, unsigned short* l) {
  __builtin_amdgcn_global_load_lds(
      (const __attribute__((address_space(1))) void*)g,
      (__attribute__((address_space(3))) void*)l, 16, 0, 0);
}

// fragment read offset (elements) for logical row r, k-group kg, tile base tb
__device__ __forceinline__ int frag_off(int tb, int r, int kg) {
  return tb + r * 32 + ((kg ^ ((r >> 1) & 3)) << 3);
}

// ------------------------------- A fp32 -> bf16 pre-pass (stacked, padded)
__global__ __launch_bounds__(256) void c2bf_k(
    const float* __restrict__ A0, const float* __restrict__ A1,
    const float* __restrict__ A2, const float* __restrict__ A3,
    unsigned short* __restrict__ Abf)
{
  const int row = blockIdx.x * 4 + (threadIdx.x >> 6);   // 0..61439
  const int lane = threadIdx.x & 63;
  const int c = row / 15360;
  const int lr = row - c * 15360;
  const float* A = (c == 0) ? A0 : (c == 1) ? A1 : (c == 2) ? A2 : A3;

  float4 f0 = make_float4(0.f, 0.f, 0.f, 0.f), f1 = f0;
  if (lane < 63) {
    const float* p = A + (size_t)lr * 504 + lane * 8;
    f0 = *reinterpret_cast<const float4*>(p);
    f1 = *reinterpret_cast<const float4*>(p + 4);
  }
  bf16x8 o;
  o[0] = (short)f2bf(f0.x); o[1] = (short)f2bf(f0.y);
  o[2] = (short)f2bf(f0.z); o[3] = (short)f2bf(f0.w);
  o[4] = (short)f2bf(f1.x); o[5] = (short)f2bf(f1.y);
  o[6] = (short)f2bf(f1.z); o[7] = (short)f2bf(f1.w);
  *reinterpret_cast<bf16x8*>(Abf + (size_t)row * 512 + lane * 8) = o;
}

// --------------------------------------------- weight transpose+split pass
struct WS8 {
  const float* W[8];
  unsigned short* Th[8];
  unsigned short* Tl[8];
  int K[8], N[8], Kp[8];
};

__global__ __launch_bounds__(256) void wsplit_all_k(WS8 d) {
  const int zi = blockIdx.z;
  const float* W = d.W[zi];
  unsigned short* Th = d.Th[zi];
  unsigned short* Tl = d.Tl[zi];
  const int K = d.K[zi], N = d.N[zi], Kp = d.Kp[zi];
  const int n0 = blockIdx.x * 64, k0 = blockIdx.y * 64;
  if (n0 >= N || k0 >= Kp) return;

  __shared__ float T[64][65];
  const int t = threadIdx.x;
  {
    const int lk = t >> 2;
    const int ln = (t & 3) * 16;
    const int gk = k0 + lk;
#pragma unroll
    for (int j = 0; j < 16; j += 4) {
      float4 v = make_float4(0.f, 0.f, 0.f, 0.f);
      const int gn = n0 + ln + j;
      if (gk < K) {
        if (gn + 3 < N) {
          v = *reinterpret_cast<const float4*>(W + (size_t)gk * N + gn);
        } else {
          const float* p = W + (size_t)gk * N;
          if (gn     < N) v.x = p[gn];
          if (gn + 1 < N) v.y = p[gn + 1];
          if (gn + 2 < N) v.z = p[gn + 2];
          if (gn + 3 < N) v.w = p[gn + 3];
        }
      }
      T[lk][ln + j + 0] = v.x; T[lk][ln + j + 1] = v.y;
      T[lk][ln + j + 2] = v.z; T[lk][ln + j + 3] = v.w;
    }
  }
  __syncthreads();
  {
    const int rn = t >> 2;
    const int rk = (t & 3) * 16;
    const int gn = n0 + rn;
    if (gn < N) {
      size_t base = (size_t)gn * Kp + k0 + rk;
#pragma unroll
      for (int j = 0; j < 16; ++j) {
        float x = T[rk + j][rn];
        unsigned short h = f2bf(x);
        unsigned short l = f2bf(x - bf2f(h));
        Th[base + j] = h;
        Tl[base + j] = l;
      }
    }
  }
}

// --------------------------------------------------- MLP GEMM: x1, 128x64
// acc += Ah*Bh (bf16-hi activations AND weights). gl_lds staging,
// double-buffered 24KB LDS, 1 barrier/iter, prefetch-early.
__global__ __launch_bounds__(256) void gemm_n64_x1(
    const unsigned short* __restrict__ Ah, int lda,
    const unsigned short* __restrict__ Bh, int ldb,
    const float* __restrict__ bias, float* __restrict__ Cf,
    unsigned short* __restrict__ Ch,
    int ldc, int M, int N, int Ktot, int kslice, int relu)
{
  __shared__ unsigned short sm[12288];   // 2 x (Ah@0 Bh@4096)

  const int t = threadIdx.x;
  const int bm = blockIdx.x * 128;
  const int bn = blockIdx.y * 64;
  const int z  = blockIdx.z;
  const int koff = z * kslice;
  const int klen = min(kslice, Ktot - koff);

  const int lane = t & 63, wave = t >> 6;
  const int wm = (wave >> 1) * 64, wn = (wave & 1) * 32;
  const int fr = lane & 15, kg = lane >> 4;

  const unsigned short* sp[3];
  int dpo[3];
#pragma unroll
  for (int q = 0; q < 3; ++q) {
    const int j = wave + 4 * q;
    int tile, i;
    if (j < 8) { tile = 0; i = j; }
    else       { tile = 1; i = j - 8; }
    const int row = i * 16 + (lane >> 2);
    const int chunk = (lane & 3) ^ ((row >> 1) & 3);
    const unsigned short* base = (tile == 0) ? Ah : Bh;
    const int ld = (tile == 0) ? lda : ldb;
    const int grow = (tile == 0) ? (bm + row) : min(bn + row, N - 1);
    const int tb = (tile == 0) ? 0 : 4096;
    sp[q] = base + (size_t)grow * ld + koff + chunk * 8;
    dpo[q] = tb + i * 512 + lane * 8;
  }

  int offA[4], offB[2];
#pragma unroll
  for (int i = 0; i < 4; ++i) offA[i] = frag_off(0, wm + i * 16 + fr, kg);
#pragma unroll
  for (int i = 0; i < 2; ++i) offB[i] = frag_off(4096, wn + i * 16 + fr, kg);

  f32x4 acc[4][2] = {};
#pragma unroll
  for (int q = 0; q < 3; ++q) gl_lds16(sp[q], sm + dpo[q]);

  int cur = 0;
  for (int k0 = 0; k0 < klen; k0 += 32) {
    __syncthreads();                     // buf[cur] staged
    if (k0 + 32 < klen) {
      unsigned short* nb = sm + (cur ^ 1) * 6144;
#pragma unroll
      for (int q = 0; q < 3; ++q) { sp[q] += 32; gl_lds16(sp[q], nb + dpo[q]); }
    }
    const unsigned short* s = sm + cur * 6144;
    bf16x8 ah[4], bh[2];
#pragma unroll
    for (int i = 0; i < 4; ++i)
      ah[i] = *reinterpret_cast<const bf16x8*>(s + offA[i]);
#pragma unroll
    for (int i = 0; i < 2; ++i)
      bh[i] = *reinterpret_cast<const bf16x8*>(s + offB[i]);
#pragma unroll
    for (int mi = 0; mi < 4; ++mi)
#pragma unroll
      for (int ni = 0; ni < 2; ++ni)
        acc[mi][ni] = __builtin_amdgcn_mfma_f32_16x16x32_bf16(ah[mi], bh[ni], acc[mi][ni], 0, 0, 0);
    cur ^= 1;
  }

#pragma unroll
  for (int mi = 0; mi < 4; ++mi) {
#pragma unroll
    for (int ni = 0; ni < 2; ++ni) {
      const int col = bn + wn + ni * 16 + fr;
      if (col >= N) continue;
      const int row0 = bm + wm + mi * 16 + kg * 4;
      const float bv = bias ? bias[col] : 0.f;
      if (Cf) {
        float* Cz = Cf + (size_t)z * (size_t)M * (size_t)N;
#pragma unroll
        for (int r = 0; r < 4; ++r) {
          float v = acc[mi][ni][r] + bv;
          if (relu) v = fmaxf(v, 0.f);
          Cz[(size_t)(row0 + r) * ldc + col] = v;
        }
      } else {
#pragma unroll
        for (int r = 0; r < 4; ++r) {
          float v = acc[mi][ni][r] + bv;
          if (relu) v = fmaxf(v, 0.f);
          Ch[(size_t)(row0 + r) * ldc + col] = f2bf(v);
        }
      }
    }
  }
}

// ---- embed GEMM: x1 (Ah*Bh), all-bf16, all-gl_lds, 128x128 tile,
// dbuf 32KB LDS, 1 barrier/iter. A = Abf[61440][512]; TAN bf16-hi out.
__global__ __launch_bounds__(256) void gemm_embed1(
    const unsigned short* __restrict__ Abf, const unsigned short* __restrict__ EW,
    const float* __restrict__ b_embed, unsigned short* __restrict__ TAN)
{
  __shared__ unsigned short sm[16384];   // 2 x (Ah@0 Bh@4096)

  const int t = threadIdx.x;
  const int bx = blockIdx.x;
  const int bm = bx * 128;               // global row into Abf/TAN
  const int bn = blockIdx.y * 128;       // 0 or 128
  const int c  = bx / 120;
  const unsigned short* Bh = EW + (size_t)c * 262144u;
  const float* bias = b_embed + c * 256;

  const int lane = t & 63, wave = t >> 6;
  const int wm = (wave >> 1) * 64, wn = (wave & 1) * 64;
  const int fr = lane & 15, kg = lane >> 4;

  const unsigned short* sp[4];
  int dpo[4];
#pragma unroll
  for (int q = 0; q < 4; ++q) {
    const int j = wave + 4 * q;
    const int tile = j >> 3;
    const int i = j & 7;
    const int row = i * 16 + (lane >> 2);
    const int chunk = (lane & 3) ^ ((row >> 1) & 3);
    const unsigned short* base = (tile == 0) ? Abf : Bh;
    const int grow = (tile == 0) ? (bm + row) : (bn + row);
    const int tb = tile * 4096;
    sp[q] = base + (size_t)grow * 512 + chunk * 8;
    dpo[q] = tb + i * 512 + lane * 8;
  }

  int offA[4], offB[4];
#pragma unroll
  for (int i = 0; i < 4; ++i) {
    offA[i] = frag_off(0,    wm + i * 16 + fr, kg);
    offB[i] = frag_off(4096, wn + i * 16 + fr, kg);
  }

  f32x4 acc[4][4] = {};
#pragma unroll
  for (int q = 0; q < 4; ++q) gl_lds16(sp[q], sm + dpo[q]);

  int cur = 0;
  for (int k0 = 0; k0 < 512; k0 += 32) {
    __syncthreads();                     // buf[cur] staged (vmcnt drained)
    if (k0 + 32 < 512) {
      unsigned short* nb = sm + (cur ^ 1) * 8192;
#pragma unroll
      for (int q = 0; q < 4; ++q) { sp[q] += 32; gl_lds16(sp[q], nb + dpo[q]); }
    }
    const unsigned short* s = sm + cur * 8192;
    bf16x8 ah[4], bh[4];
#pragma unroll
    for (int i = 0; i < 4; ++i) {
      ah[i] = *reinterpret_cast<const bf16x8*>(s + offA[i]);
      bh[i] = *reinterpret_cast<const bf16x8*>(s + offB[i]);
    }
#pragma unroll
    for (int mi = 0; mi < 4; ++mi)
#pragma unroll
      for (int ni = 0; ni < 4; ++ni)
        acc[mi][ni] = __builtin_amdgcn_mfma_f32_16x16x32_bf16(ah[mi], bh[ni], acc[mi][ni], 0, 0, 0);
    cur ^= 1;
  }

#pragma unroll
  for (int mi = 0; mi < 4; ++mi) {
#pragma unroll
    for (int ni = 0; ni < 4; ++ni) {
      const int col = bn + wn + ni * 16 + fr;
      const int row0 = bm + wm + mi * 16 + kg * 4;
      const float bv = bias[col];
#pragma unroll
      for (int r = 0; r < 4; ++r)
        TAN[(size_t)(row0 + r) * 256 + col] = f2bf(acc[mi][ni][r] + bv);
    }
  }
}

// ------------------------ LayerNorm + expmap0 -> Z (wave/row, bf16 TAN in)
__global__ __launch_bounds__(256) void ln_expmap0_k(
    const unsigned short* __restrict__ TAN, const float* __restrict__ gamma,
    const float* __restrict__ beta, float* __restrict__ Z)
{
  const int row = blockIdx.x * 4 + (threadIdx.x >> 6);   // b*30 + n
  const int lane = threadIdx.x & 63;
  const int b = row / 30;
  const int n = row % 30;

  float4 tc[4];
  float4 ts = make_float4(0.f, 0.f, 0.f, 0.f);
#pragma unroll
  for (int c = 0; c < 4; ++c) {
    ushort4 xu = *reinterpret_cast<const ushort4*>(
        TAN + ((size_t)c * 15360 + row) * 256 + lane * 4);
    float4 x = make_float4(bf2f(xu.x), bf2f(xu.y), bf2f(xu.z), bf2f(xu.w));
    float mu = wave_sum(x.x + x.y + x.z + x.w) * (1.f / 256.f);
    float4 xm = make_float4(x.x - mu, x.y - mu, x.z - mu, x.w - mu);
    float var = wave_sum(xm.x * xm.x + xm.y * xm.y + xm.z * xm.z + xm.w * xm.w)
                * (1.f / 256.f);
    float rs = rsqrtf(var + 1e-5f);
    float4 g = *reinterpret_cast<const float4*>(gamma + c * 256 + lane * 4);
    float4 be = *reinterpret_cast<const float4*>(beta + c * 256 + lane * 4);
    float4 tv = make_float4(xm.x * rs * g.x + be.x, xm.y * rs * g.y + be.y,
                            xm.z * rs * g.z + be.z, xm.w * rs * g.w + be.w);
    tc[c] = tv;
    ts.x += tv.x; ts.y += tv.y; ts.z += tv.z; ts.w += tv.w;
  }
#pragma unroll
  for (int g5 = 0; g5 < 5; ++g5) {
    float4 v = (g5 == 0) ? ts : tc[g5 - 1];
    float n2 = wave_sum(v.x * v.x + v.y * v.y + v.z * v.z + v.w * v.w);
    float nn = fmaxf(sqrtf(n2), EPS_F);
    float th = tanhf(nn);
    float w = th / nn;
    if (th > MAX_NORM_F) w *= MAX_NORM_F / fmaxf(th, EPS_F);
    float4 o = make_float4(v.x * w, v.y * w, v.z * w, v.w * w);
    *reinterpret_cast<float4*>(
        Z + (((size_t)g5 * 512 + b) * 38 + n) * 256 + lane * 4) = o;
  }
}

// ------------------------------------------------ per-pair logmap (1 wave)
__device__ __forceinline__ float4 pair_log(const float* zr, int c, int lane) {
  float4 x = *reinterpret_cast<const float4*>(zr + (size_t)c * 256 + lane * 4);
  float4 y = *reinterpret_cast<const float4*>(zr + (size_t)(c + 1) * 256 + lane * 4);
  float x2 = wave_sum(x.x * x.x + x.y * x.y + x.z * x.z + x.w * x.w);
  float y2 = wave_sum(y.x * y.x + y.y * y.y + y.z * y.z + y.w * y.w);
  float xy = wave_sum(x.x * y.x + x.y * y.y + x.z * y.z + x.w * y.w);
  float a  = 1.f - 2.f * xy + y2;
  float bb = 1.f - x2;
  float den = fmaxf(1.f - 2.f * xy + x2 * y2, EPS_F);
  float inv = 1.f / den;
  float4 u;
  u.x = (bb * y.x - a * x.x) * inv;
  u.y = (bb * y.y - a * x.y) * inv;
  u.z = (bb * y.z - a * x.z) * inv;
  u.w = (bb * y.w - a * x.w) * inv;
  float u2 = wave_sum(u.x * u.x + u.y * u.y + u.z * u.z + u.w * u.w);
  float un = fmaxf(sqrtf(u2), EPS_F);
  float coef = fmaxf(1.f - x2, EPS_F) * atanhf(fminf(un, 1.f - 1e-7f)) / un;
  float4 o;
  o.x = coef * u.x; o.y = coef * u.y; o.z = coef * u.z; o.w = coef * u.w;
  return o;
}

__device__ __forceinline__ float4 logmap0_col(const float* zr, int c, int lane) {
  float4 z = *reinterpret_cast<const float4*>(zr + (size_t)c * 256 + lane * 4);
  float z2 = wave_sum(z.x * z.x + z.y * z.y + z.z * z.z + z.w * z.w);
  float nz = fmaxf(sqrtf(z2), EPS_F);
  float cc = atanhf(fminf(nz, 1.f - 1e-7f)) / nz;
  float4 o;
  o.x = cc * z.x; o.y = cc * z.y; o.z = cc * z.z; o.w = cc * z.w;
  return o;
}

// -------- velocity t=0: 4 waves per row, pairs split across waves.
__global__ __launch_bounds__(256) void vel_feat_t0_k(
    const float* __restrict__ Z, unsigned short* __restrict__ Fh,
    float* __restrict__ VSUM)
{
  __shared__ float red[4][256];
  const int r = blockIdx.x;
  const int wave = threadIdx.x >> 6, lane = threadIdx.x & 63;
  const float* zr = Z + (size_t)r * 38 * 256;

  float4 vs = make_float4(0.f, 0.f, 0.f, 0.f);
  for (int j = wave; j < 29; j += 4) {
    float4 p = pair_log(zr, j, lane);
    vs.x += p.x; vs.y += p.y; vs.z += p.z; vs.w += p.w;
  }
  *reinterpret_cast<float4*>(&red[wave][lane * 4]) = vs;
  __syncthreads();

  const size_t fb = (size_t)r * 768 + lane * 4;
  if (wave == 0) {
    float4 a0 = *reinterpret_cast<const float4*>(&red[0][lane * 4]);
    float4 a1 = *reinterpret_cast<const float4*>(&red[1][lane * 4]);
    float4 a2 = *reinterpret_cast<const float4*>(&red[2][lane * 4]);
    float4 a3 = *reinterpret_cast<const float4*>(&red[3][lane * 4]);
    vs.x = a0.x + a1.x + a2.x + a3.x;
    vs.y = a0.y + a1.y + a2.y + a3.y;
    vs.z = a0.z + a1.z + a2.z + a3.z;
    vs.w = a0.w + a1.w + a2.w + a3.w;
    *reinterpret_cast<float4*>(VSUM + (size_t)r * 256 + lane * 4) = vs;
    const float s29 = 1.f / 29.f;
    float4 o;
    o.x = vs.x * s29; o.y = vs.y * s29; o.z = vs.z * s29; o.w = vs.w * s29;
    store_hi4(Fh, fb + 512, o);
  } else if (wave == 1) {
    float4 fl = logmap0_col(zr, 29, lane);   // z_last
    store_hi4(Fh, fb, fl);
  } else if (wave == 2) {
    float4 fp = logmap0_col(zr, 28, lane);   // z_prev
    store_hi4(Fh, fb + 256, fp);
  }
}

// --------- fused: z_next = expmap(z_last, sum VP + b3); writes
// U[r*8+t] = logmap0(z_next) (stage-C fusion); then (if t<7) incremental
// velocity + FEAT for step t+1. 2 waves per row (role 0 main, 1 helper).
__global__ __launch_bounds__(256) void expmap_vel_fused_k(
    float* __restrict__ Z, const float* __restrict__ VP,
    const float* __restrict__ b3, unsigned short* __restrict__ Fh,
    float* __restrict__ VSUM, unsigned short* __restrict__ Uh, int t)
{
  __shared__ float pmL[2][256];
  const int wave = threadIdx.x >> 6, lane = threadIdx.x & 63;
  const int rloc = wave >> 1;            // 0..1
  const int role = wave & 1;             // 0 main, 1 helper
  const int r = blockIdx.x * 2 + rloc;
  float* zr = Z + (size_t)r * 38 * 256;
  const size_t fb = (size_t)r * 768 + lane * 4;

  float4 res, u;
  float coef = 0.f, rn = 0.f, x2 = 0.f;

  if (role == 0) {
    float4 x = *reinterpret_cast<const float4*>(zr + (size_t)(t + 29) * 256 + lane * 4);
    float4 v = *reinterpret_cast<const float4*>(b3 + lane * 4);
#pragma unroll
    for (int p = 0; p < 4; ++p) {
      float4 a = *reinterpret_cast<const float4*>(
          VP + (size_t)p * 655360u + (size_t)r * 256 + lane * 4);
      v.x += a.x; v.y += a.y; v.z += a.z; v.w += a.w;
    }
    x2 = wave_sum(x.x * x.x + x.y * x.y + x.z * x.z + x.w * x.w);
    float v2 = wave_sum(v.x * v.x + v.y * v.y + v.z * v.z + v.w * v.w);
    float xv = wave_sum(x.x * v.x + x.y * v.y + x.z * v.z + x.w * v.w);

    float vn = fmaxf(sqrtf(v2), EPS_F);
    float lamx = 2.f / fmaxf(1.f - x2, EPS_F);
    float s = tanhf(0.5f * lamx * vn) / vn;
    float xy = s * xv;
    float y2 = s * s * v2;
    float a  = 1.f + 2.f * xy + y2;
    float bb = 1.f - x2;
    float den = fmaxf(1.f + 2.f * xy + x2 * y2, EPS_F);
    float inv = 1.f / den;
    res.x = (a * x.x + bb * s * v.x) * inv;
    res.y = (a * x.y + bb * s * v.y) * inv;
    res.z = (a * x.z + bb * s * v.z) * inv;
    res.w = (a * x.w + bb * s * v.w) * inv;
    float r2 = wave_sum(res.x * res.x + res.y * res.y + res.z * res.z + res.w * res.w);
    rn = sqrtf(r2);
    if (rn > MAX_NORM_F) {
      float sc = MAX_NORM_F / fmaxf(rn, EPS_F);
      res.x *= sc; res.y *= sc; res.z *= sc; res.w *= sc;
      r2 = MAX_NORM_F * MAX_NORM_F;
      rn = MAX_NORM_F;
    }
    *reinterpret_cast<float4*>(zr + (size_t)(t + 30) * 256 + lane * 4) = res;

    // stage-C fusion: U[r*8 + t] = logmap0(z_next) = cl * res
    {
      float rnp = fmaxf(rn, EPS_F);
      float cl = atanhf(fminf(rnp, 1.f - 1e-7f)) / rnp;
      float4 o;
      o.x = cl * res.x; o.y = cl * res.y; o.z = cl * res.z; o.w = cl * res.w;
      store_hi4(Uh, ((size_t)(r * 8 + t)) * 256 + lane * 4, o);
      if (t < 7) store_hi4(Fh, fb, o);   // FEAT z_last column (same value)
    }

    if (t < 7) {
      float xyn = wave_sum(x.x * res.x + x.y * res.y + x.z * res.z + x.w * res.w);
      float an  = 1.f - 2.f * xyn + r2;
      float bbn = 1.f - x2;
      float denn = fmaxf(1.f - 2.f * xyn + x2 * r2, EPS_F);
      float invn = 1.f / denn;
      u.x = (bbn * res.x - an * x.x) * invn;
      u.y = (bbn * res.y - an * x.y) * invn;
      u.z = (bbn * res.z - an * x.z) * invn;
      u.w = (bbn * res.w - an * x.w) * invn;
      float u2 = wave_sum(u.x * u.x + u.y * u.y + u.z * u.z + u.w * u.w);
      float un = fmaxf(sqrtf(u2), EPS_F);
      coef = fmaxf(1.f - x2, EPS_F) * atanhf(fminf(un, 1.f - 1e-7f)) / un;
    }
  } else if (t < 7) {
    // helper: pm (independent of res) + cp-FEAT column
    float4 pm = pair_log(zr, t, lane);
    *reinterpret_cast<float4*>(&pmL[rloc][lane * 4]) = pm;
    float4 x = *reinterpret_cast<const float4*>(zr + (size_t)(t + 29) * 256 + lane * 4);
    float hx2 = wave_sum(x.x * x.x + x.y * x.y + x.z * x.z + x.w * x.w);
    float nx = fmaxf(sqrtf(hx2), EPS_F);
    float cp = atanhf(fminf(nx, 1.f - 1e-7f)) / nx;
    float4 o;
    o.x = cp * x.x; o.y = cp * x.y; o.z = cp * x.z; o.w = cp * x.w;
    store_hi4(Fh, fb + 256, o);
  }

  __syncthreads();

  if (role == 0 && t < 7) {
    float4 pm = *reinterpret_cast<const float4*>(&pmL[rloc][lane * 4]);
    float4 vs = *reinterpret_cast<const float4*>(VSUM + (size_t)r * 256 + lane * 4);
    vs.x += coef * u.x - pm.x; vs.y += coef * u.y - pm.y;
    vs.z += coef * u.z - pm.z; vs.w += coef * u.w - pm.w;
    *reinterpret_cast<float4*>(VSUM + (size_t)r * 256 + lane * 4) = vs;

    const float s29 = 1.f / 29.f;
    float4 o;
    o.x = vs.x * s29; o.y = vs.y * s29; o.z = vs.z * s29; o.w = vs.w * s29;
    store_hi4(Fh, fb + 512, o);
  }
}

// ---------------------------------------------------------------- launcher
extern "C" void kernel_launch(void* const* d_in, const int* in_sizes, int n_in,
                              void* d_out, int out_size, void* d_ws, size_t ws_size,
                              hipStream_t stream)
{
  const float* c0 = (const float*)d_in[0];
  const float* c1 = (const float*)d_in[1];
  const float* c2 = (const float*)d_in[2];
  const float* c3 = (const float*)d_in[3];
  const float* W_embed = (const float*)d_in[4];
  const float* b_embed = (const float*)d_in[5];
  const float* ln_g    = (const float*)d_in[6];
  const float* ln_b    = (const float*)d_in[7];
  const float* W1 = (const float*)d_in[8];
  const float* b1 = (const float*)d_in[9];
  const float* W2 = (const float*)d_in[10];
  const float* b2 = (const float*)d_in[11];
  const float* W3 = (const float*)d_in[12];
  const float* b3 = (const float*)d_in[13];
  const float* W_out = (const float*)d_in[14];
  const float* b_out = (const float*)d_in[15];
  float* out = (float*)d_out;
  float* ws  = (float*)d_ws;

  // ---- ws layout (proven footprint).
  float* Z = ws;
  unsigned short* Abf = (unsigned short*)ws;        // aliases Z (stage A only)
  unsigned short* Rs = (unsigned short*)(ws + 24903680u);
  unsigned short* TAN = Rs + 20000000u;             // 4*15360*256 shorts
  unsigned short* W1h = Rs;                         // [1024][768]
  unsigned short* W1l = Rs + 786432u;
  unsigned short* W2h = Rs + 1572864u;              // [1024][1024]
  unsigned short* W2l = Rs + 2621440u;
  unsigned short* W3h = Rs + 3670016u;              // [256][1024]
  unsigned short* W3l = Rs + 3932160u;
  unsigned short* Woh = Rs + 4194304u;              // [504][256]
  unsigned short* Wol = Rs + 4323328u;
  unsigned short* FEATh = Rs + 4452352u;            // [2560][768]
  unsigned short* H1h = Rs + 6418432u;              // [2560][1024]
  unsigned short* H2h = Rs + 9039872u;              // [2560][1024]
  unsigned short* Uh  = Rs + 11661312u;             // [20480][256]
  float* VP   = ws + 34338816u;                     // 4 x 2560*256 parts
  float* VSUM = ws + 39581696u;                     // 2560*256

  unsigned short* EW = (unsigned short*)d_out;      // embed weights scratch

  dim3 blk(256);

  // Stage A: A->bf16 pre-pass + all 8 weight splits -> embed GEMM -> LN
  c2bf_k<<<dim3(15360), blk, 0, stream>>>(c0, c1, c2, c3, Abf);
  {
    WS8 d;
    for (int c = 0; c < 4; ++c) {
      d.W[c] = W_embed + (size_t)c * 504 * 256;
      d.Th[c] = EW + (size_t)c * 262144u;
      d.Tl[c] = EW + (size_t)c * 262144u + 131072u;
      d.K[c] = 504; d.N[c] = 256; d.Kp[c] = 512;
    }
    d.W[4] = W1;    d.Th[4] = W1h; d.Tl[4] = W1l; d.K[4] = 768;  d.N[4] = 1024; d.Kp[4] = 768;
    d.W[5] = W2;    d.Th[5] = W2h; d.Tl[5] = W2l; d.K[5] = 1024; d.N[5] = 1024; d.Kp[5] = 1024;
    d.W[6] = W3;    d.Th[6] = W3h; d.Tl[6] = W3l; d.K[6] = 1024; d.N[6] = 256;  d.Kp[6] = 1024;
    d.W[7] = W_out; d.Th[7] = Woh; d.Tl[7] = Wol; d.K[7] = 256;  d.N[7] = 504;  d.Kp[7] = 256;
    wsplit_all_k<<<dim3(16, 16, 8), blk, 0, stream>>>(d);
  }
  gemm_embed1<<<dim3(480, 2), blk, 0, stream>>>(Abf, EW, b_embed, TAN);
  ln_expmap0_k<<<dim3(3840), blk, 0, stream>>>(TAN, ln_g, ln_b, Z);

  // Stage B: 8 recurrent steps (x1 weights; vel/feat + U-write fused)
  vel_feat_t0_k<<<dim3(2560), blk, 0, stream>>>(Z, FEATh, VSUM);
  for (int t = 0; t < 8; ++t) {
    gemm_n64_x1<<<dim3(20, 16, 1), blk, 0, stream>>>(
        FEATh, 768, W1h, 768, b1, nullptr, H1h,
        1024, 2560, 1024, 768, 768, 1);
    gemm_n64_x1<<<dim3(20, 16, 1), blk, 0, stream>>>(
        H1h, 1024, W2h, 1024, b2, nullptr, H2h,
        1024, 2560, 1024, 1024, 1024, 1);
    gemm_n64_x1<<<dim3(20, 4, 4), blk, 0, stream>>>(
        H2h, 1024, W3h, 1024, nullptr, VP, nullptr,
        256, 2560, 256, 1024, 256, 0);
    expmap_vel_fused_k<<<dim3(1280), blk, 0, stream>>>(
        Z, VP, b3, FEATh, VSUM, Uh, t);
  }

  // Stage C: final projection into d_out (U written by step loop)
  gemm_n64_x1<<<dim3(160, 8, 1), blk, 0, stream>>>(
      Uh, 256, Woh, 256, b_out, out, nullptr,
      504, 20480, 504, 256, 256, 0);
}

// Round 15
// 558.283 us; speedup vs baseline: 3.3734x; 1.0106x over previous
//
#include <hip/hip_runtime.h>
#include <cstddef>
#include <cstdint>

#define EPS_F 1e-7f
#define MAX_NORM_F 0.99999f   // (1 - 1e-5) / SC, SC = 1

typedef __attribute__((ext_vector_type(8))) short bf16x8;  // 8 bf16 (4 VGPR)
typedef __attribute__((ext_vector_type(4))) float f32x4;

// ---------------------------------------------------------------- helpers
__device__ __forceinline__ unsigned short f2bf(float x) {
  unsigned int u = __float_as_uint(x);
  unsigned int r = u + 0x7FFFu + ((u >> 16) & 1u);   // RNE (no NaN in data)
  return (unsigned short)(r >> 16);
}
__device__ __forceinline__ float bf2f(unsigned short h) {
  return __uint_as_float(((unsigned int)h) << 16);
}

__device__ __forceinline__ float wave_sum(float v) {
#pragma unroll
  for (int off = 32; off; off >>= 1) v += __shfl_xor(v, off);
  return v;
}

__device__ __forceinline__ void store_hi4(unsigned short* H, size_t idx, float4 v) {
  ushort4 h;
  h.x = f2bf(v.x); h.y = f2bf(v.y); h.z = f2bf(v.z); h.w = f2bf(v.w);
  *reinterpret_cast<ushort4*>(H + idx) = h;
}

// async global->LDS, 16B per lane; LDS dest = uniform base + lane*16
__device__ __forceinline__ void gl_lds16(const unsigned short* g, unsigned short* l) {
  __builtin_amdgcn_global_load_lds(
      (const __attribute__((address_space(1))) void*)g,
      (__attribute__((address_space(3))) void*)l, 16, 0, 0);
}

// fragment read offset (elements) for logical row r, k-group kg, tile base tb
__device__ __forceinline__ int frag_off(int tb, int r, int kg) {
  return tb + r * 32 + ((kg ^ ((r >> 1) & 3)) << 3);
}

// ------------- fused pre-pass: A fp32->bf16 (15360 blocks) + weight
// transpose/split (2048 blocks), one launch. bid<15360: c2bf; else wsplit.
struct WS8 {
  const float* W[8];
  unsigned short* Th[8];
  unsigned short* Tl[8];
  int K[8], N[8], Kp[8];
};

__global__ __launch_bounds__(256) void prep_k(
    WS8 d,
    const float* __restrict__ A0, const float* __restrict__ A1,
    const float* __restrict__ A2, const float* __restrict__ A3,
    unsigned short* __restrict__ Abf)
{
  __shared__ float T[64][65];
  const int bid = blockIdx.x;
  const int t = threadIdx.x;

  if (bid < 15360) {
    // ---- c2bf: 4 rows per block (1 per wave)
    const int row = bid * 4 + (t >> 6);
    const int lane = t & 63;
    const int c = row / 15360;
    const int lr = row - c * 15360;
    const float* A = (c == 0) ? A0 : (c == 1) ? A1 : (c == 2) ? A2 : A3;

    float4 f0 = make_float4(0.f, 0.f, 0.f, 0.f), f1 = f0;
    if (lane < 63) {
      const float* p = A + (size_t)lr * 504 + lane * 8;
      f0 = *reinterpret_cast<const float4*>(p);
      f1 = *reinterpret_cast<const float4*>(p + 4);
    }
    bf16x8 o;
    o[0] = (short)f2bf(f0.x); o[1] = (short)f2bf(f0.y);
    o[2] = (short)f2bf(f0.z); o[3] = (short)f2bf(f0.w);
    o[4] = (short)f2bf(f1.x); o[5] = (short)f2bf(f1.y);
    o[6] = (short)f2bf(f1.z); o[7] = (short)f2bf(f1.w);
    *reinterpret_cast<bf16x8*>(Abf + (size_t)row * 512 + lane * 8) = o;
    return;
  }

  // ---- wsplit: decode (n0, k0, zi) from flattened index
  const int w = bid - 15360;
  const int zi = w >> 8;                 // 256 blocks per weight (16x16)
  const int rem = w & 255;
  const int n0 = (rem & 15) * 64;
  const int k0 = (rem >> 4) * 64;
  const float* W = d.W[zi];
  unsigned short* Th = d.Th[zi];
  unsigned short* Tl = d.Tl[zi];
  const int K = d.K[zi], N = d.N[zi], Kp = d.Kp[zi];
  if (n0 >= N || k0 >= Kp) return;

  {
    const int lk = t >> 2;
    const int ln = (t & 3) * 16;
    const int gk = k0 + lk;
#pragma unroll
    for (int j = 0; j < 16; j += 4) {
      float4 v = make_float4(0.f, 0.f, 0.f, 0.f);
      const int gn = n0 + ln + j;
      if (gk < K) {
        if (gn + 3 < N) {
          v = *reinterpret_cast<const float4*>(W + (size_t)gk * N + gn);
        } else {
          const float* p = W + (size_t)gk * N;
          if (gn     < N) v.x = p[gn];
          if (gn + 1 < N) v.y = p[gn + 1];
          if (gn + 2 < N) v.z = p[gn + 2];
          if (gn + 3 < N) v.w = p[gn + 3];
        }
      }
      T[lk][ln + j + 0] = v.x; T[lk][ln + j + 1] = v.y;
      T[lk][ln + j + 2] = v.z; T[lk][ln + j + 3] = v.w;
    }
  }
  __syncthreads();
  {
    const int rn = t >> 2;
    const int rk = (t & 3) * 16;
    const int gn = n0 + rn;
    if (gn < N) {
      size_t base = (size_t)gn * Kp + k0 + rk;
#pragma unroll
      for (int j = 0; j < 16; ++j) {
        float x = T[rk + j][rn];
        unsigned short h = f2bf(x);
        unsigned short l = f2bf(x - bf2f(h));
        Th[base + j] = h;
        Tl[base + j] = l;
      }
    }
  }
}

// --------------------------------------------------- MLP GEMM: x1, 128x64
// acc += Ah*Bh (bf16-hi activations AND weights). gl_lds staging,
// double-buffered 24KB LDS, 1 barrier/iter, prefetch-early.
__global__ __launch_bounds__(256) void gemm_n64_x1(
    const unsigned short* __restrict__ Ah, int lda,
    const unsigned short* __restrict__ Bh, int ldb,
    const float* __restrict__ bias, float* __restrict__ Cf,
    unsigned short* __restrict__ Ch,
    int ldc, int M, int N, int Ktot, int kslice, int relu)
{
  __shared__ unsigned short sm[12288];   // 2 x (Ah@0 Bh@4096)

  const int t = threadIdx.x;
  const int bm = blockIdx.x * 128;
  const int bn = blockIdx.y * 64;
  const int z  = blockIdx.z;
  const int koff = z * kslice;
  const int klen = min(kslice, Ktot - koff);

  const int lane = t & 63, wave = t >> 6;
  const int wm = (wave >> 1) * 64, wn = (wave & 1) * 32;
  const int fr = lane & 15, kg = lane >> 4;

  const unsigned short* sp[3];
  int dpo[3];
#pragma unroll
  for (int q = 0; q < 3; ++q) {
    const int j = wave + 4 * q;
    int tile, i;
    if (j < 8) { tile = 0; i = j; }
    else       { tile = 1; i = j - 8; }
    const int row = i * 16 + (lane >> 2);
    const int chunk = (lane & 3) ^ ((row >> 1) & 3);
    const unsigned short* base = (tile == 0) ? Ah : Bh;
    const int ld = (tile == 0) ? lda : ldb;
    const int grow = (tile == 0) ? (bm + row) : min(bn + row, N - 1);
    const int tb = (tile == 0) ? 0 : 4096;
    sp[q] = base + (size_t)grow * ld + koff + chunk * 8;
    dpo[q] = tb + i * 512 + lane * 8;
  }

  int offA[4], offB[2];
#pragma unroll
  for (int i = 0; i < 4; ++i) offA[i] = frag_off(0, wm + i * 16 + fr, kg);
#pragma unroll
  for (int i = 0; i < 2; ++i) offB[i] = frag_off(4096, wn + i * 16 + fr, kg);

  f32x4 acc[4][2] = {};
#pragma unroll
  for (int q = 0; q < 3; ++q) gl_lds16(sp[q], sm + dpo[q]);

  int cur = 0;
  for (int k0 = 0; k0 < klen; k0 += 32) {
    __syncthreads();                     // buf[cur] staged
    if (k0 + 32 < klen) {
      unsigned short* nb = sm + (cur ^ 1) * 6144;
#pragma unroll
      for (int q = 0; q < 3; ++q) { sp[q] += 32; gl_lds16(sp[q], nb + dpo[q]); }
    }
    const unsigned short* s = sm + cur * 6144;
    bf16x8 ah[4], bh[2];
#pragma unroll
    for (int i = 0; i < 4; ++i)
      ah[i] = *reinterpret_cast<const bf16x8*>(s + offA[i]);
#pragma unroll
    for (int i = 0; i < 2; ++i)
      bh[i] = *reinterpret_cast<const bf16x8*>(s + offB[i]);
#pragma unroll
    for (int mi = 0; mi < 4; ++mi)
#pragma unroll
      for (int ni = 0; ni < 2; ++ni)
        acc[mi][ni] = __builtin_amdgcn_mfma_f32_16x16x32_bf16(ah[mi], bh[ni], acc[mi][ni], 0, 0, 0);
    cur ^= 1;
  }

#pragma unroll
  for (int mi = 0; mi < 4; ++mi) {
#pragma unroll
    for (int ni = 0; ni < 2; ++ni) {
      const int col = bn + wn + ni * 16 + fr;
      if (col >= N) continue;
      const int row0 = bm + wm + mi * 16 + kg * 4;
      const float bv = bias ? bias[col] : 0.f;
      if (Cf) {
        float* Cz = Cf + (size_t)z * (size_t)M * (size_t)N;
#pragma unroll
        for (int r = 0; r < 4; ++r) {
          float v = acc[mi][ni][r] + bv;
          if (relu) v = fmaxf(v, 0.f);
          Cz[(size_t)(row0 + r) * ldc + col] = v;
        }
      } else {
#pragma unroll
        for (int r = 0; r < 4; ++r) {
          float v = acc[mi][ni][r] + bv;
          if (relu) v = fmaxf(v, 0.f);
          Ch[(size_t)(row0 + r) * ldc + col] = f2bf(v);
        }
      }
    }
  }
}

// ---- embed GEMM: x1 (Ah*Bh), all-bf16, all-gl_lds, 128x128 tile,
// dbuf 32KB LDS, 1 barrier/iter. A = Abf[61440][512]; TAN bf16-hi out.
__global__ __launch_bounds__(256) void gemm_embed1(
    const unsigned short* __restrict__ Abf, const unsigned short* __restrict__ EW,
    const float* __restrict__ b_embed, unsigned short* __restrict__ TAN)
{
  __shared__ unsigned short sm[16384];   // 2 x (Ah@0 Bh@4096)

  const int t = threadIdx.x;
  const int bx = blockIdx.x;
  const int bm = bx * 128;               // global row into Abf/TAN
  const int bn = blockIdx.y * 128;       // 0 or 128
  const int c  = bx / 120;
  const unsigned short* Bh = EW + (size_t)c * 262144u;
  const float* bias = b_embed + c * 256;

  const int lane = t & 63, wave = t >> 6;
  const int wm = (wave >> 1) * 64, wn = (wave & 1) * 64;
  const int fr = lane & 15, kg = lane >> 4;

  const unsigned short* sp[4];
  int dpo[4];
#pragma unroll
  for (int q = 0; q < 4; ++q) {
    const int j = wave + 4 * q;
    const int tile = j >> 3;
    const int i = j & 7;
    const int row = i * 16 + (lane >> 2);
    const int chunk = (lane & 3) ^ ((row >> 1) & 3);
    const unsigned short* base = (tile == 0) ? Abf : Bh;
    const int grow = (tile == 0) ? (bm + row) : (bn + row);
    const int tb = tile * 4096;
    sp[q] = base + (size_t)grow * 512 + chunk * 8;
    dpo[q] = tb + i * 512 + lane * 8;
  }

  int offA[4], offB[4];
#pragma unroll
  for (int i = 0; i < 4; ++i) {
    offA[i] = frag_off(0,    wm + i * 16 + fr, kg);
    offB[i] = frag_off(4096, wn + i * 16 + fr, kg);
  }

  f32x4 acc[4][4] = {};
#pragma unroll
  for (int q = 0; q < 4; ++q) gl_lds16(sp[q], sm + dpo[q]);

  int cur = 0;
  for (int k0 = 0; k0 < 512; k0 += 32) {
    __syncthreads();                     // buf[cur] staged (vmcnt drained)
    if (k0 + 32 < 512) {
      unsigned short* nb = sm + (cur ^ 1) * 8192;
#pragma unroll
      for (int q = 0; q < 4; ++q) { sp[q] += 32; gl_lds16(sp[q], nb + dpo[q]); }
    }
    const unsigned short* s = sm + cur * 8192;
    bf16x8 ah[4], bh[4];
#pragma unroll
    for (int i = 0; i < 4; ++i) {
      ah[i] = *reinterpret_cast<const bf16x8*>(s + offA[i]);
      bh[i] = *reinterpret_cast<const bf16x8*>(s + offB[i]);
    }
#pragma unroll
    for (int mi = 0; mi < 4; ++mi)
#pragma unroll
      for (int ni = 0; ni < 4; ++ni)
        acc[mi][ni] = __builtin_amdgcn_mfma_f32_16x16x32_bf16(ah[mi], bh[ni], acc[mi][ni], 0, 0, 0);
    cur ^= 1;
  }

#pragma unroll
  for (int mi = 0; mi < 4; ++mi) {
#pragma unroll
    for (int ni = 0; ni < 4; ++ni) {
      const int col = bn + wn + ni * 16 + fr;
      const int row0 = bm + wm + mi * 16 + kg * 4;
      const float bv = bias[col];
#pragma unroll
      for (int r = 0; r < 4; ++r)
        TAN[(size_t)(row0 + r) * 256 + col] = f2bf(acc[mi][ni][r] + bv);
    }
  }
}

// ------------------------ LayerNorm + expmap0 -> Z (wave/row, bf16 TAN in)
__global__ __launch_bounds__(256) void ln_expmap0_k(
    const unsigned short* __restrict__ TAN, const float* __restrict__ gamma,
    const float* __restrict__ beta, float* __restrict__ Z)
{
  const int row = blockIdx.x * 4 + (threadIdx.x >> 6);   // b*30 + n
  const int lane = threadIdx.x & 63;
  const int b = row / 30;
  const int n = row % 30;

  float4 tc[4];
  float4 ts = make_float4(0.f, 0.f, 0.f, 0.f);
#pragma unroll
  for (int c = 0; c < 4; ++c) {
    ushort4 xu = *reinterpret_cast<const ushort4*>(
        TAN + ((size_t)c * 15360 + row) * 256 + lane * 4);
    float4 x = make_float4(bf2f(xu.x), bf2f(xu.y), bf2f(xu.z), bf2f(xu.w));
    float mu = wave_sum(x.x + x.y + x.z + x.w) * (1.f / 256.f);
    float4 xm = make_float4(x.x - mu, x.y - mu, x.z - mu, x.w - mu);
    float var = wave_sum(xm.x * xm.x + xm.y * xm.y + xm.z * xm.z + xm.w * xm.w)
                * (1.f / 256.f);
    float rs = rsqrtf(var + 1e-5f);
    float4 g = *reinterpret_cast<const float4*>(gamma + c * 256 + lane * 4);
    float4 be = *reinterpret_cast<const float4*>(beta + c * 256 + lane * 4);
    float4 tv = make_float4(xm.x * rs * g.x + be.x, xm.y * rs * g.y + be.y,
                            xm.z * rs * g.z + be.z, xm.w * rs * g.w + be.w);
    tc[c] = tv;
    ts.x += tv.x; ts.y += tv.y; ts.z += tv.z; ts.w += tv.w;
  }
#pragma unroll
  for (int g5 = 0; g5 < 5; ++g5) {
    float4 v = (g5 == 0) ? ts : tc[g5 - 1];
    float n2 = wave_sum(v.x * v.x + v.y * v.y + v.z * v.z + v.w * v.w);
    float nn = fmaxf(sqrtf(n2), EPS_F);
    float th = tanhf(nn);
    float w = th / nn;
    if (th > MAX_NORM_F) w *= MAX_NORM_F / fmaxf(th, EPS_F);
    float4 o = make_float4(v.x * w, v.y * w, v.z * w, v.w * w);
    *reinterpret_cast<float4*>(
        Z + (((size_t)g5 * 512 + b) * 38 + n) * 256 + lane * 4) = o;
  }
}

// ------------------------------------------------ per-pair logmap (1 wave)
__device__ __forceinline__ float4 pair_log(const float* zr, int c, int lane) {
  float4 x = *reinterpret_cast<const float4*>(zr + (size_t)c * 256 + lane * 4);
  float4 y = *reinterpret_cast<const float4*>(zr + (size_t)(c + 1) * 256 + lane * 4);
  float x2 = wave_sum(x.x * x.x + x.y * x.y + x.z * x.z + x.w * x.w);
  float y2 = wave_sum(y.x * y.x + y.y * y.y + y.z * y.z + y.w * y.w);
  float xy = wave_sum(x.x * y.x + x.y * y.y + x.z * y.z + x.w * y.w);
  float a  = 1.f - 2.f * xy + y2;
  float bb = 1.f - x2;
  float den = fmaxf(1.f - 2.f * xy + x2 * y2, EPS_F);
  float inv = 1.f / den;
  float4 u;
  u.x = (bb * y.x - a * x.x) * inv;
  u.y = (bb * y.y - a * x.y) * inv;
  u.z = (bb * y.z - a * x.z) * inv;
  u.w = (bb * y.w - a * x.w) * inv;
  float u2 = wave_sum(u.x * u.x + u.y * u.y + u.z * u.z + u.w * u.w);
  float un = fmaxf(sqrtf(u2), EPS_F);
  float coef = fmaxf(1.f - x2, EPS_F) * atanhf(fminf(un, 1.f - 1e-7f)) / un;
  float4 o;
  o.x = coef * u.x; o.y = coef * u.y; o.z = coef * u.z; o.w = coef * u.w;
  return o;
}

__device__ __forceinline__ float4 logmap0_col(const float* zr, int c, int lane) {
  float4 z = *reinterpret_cast<const float4*>(zr + (size_t)c * 256 + lane * 4);
  float z2 = wave_sum(z.x * z.x + z.y * z.y + z.z * z.z + z.w * z.w);
  float nz = fmaxf(sqrtf(z2), EPS_F);
  float cc = atanhf(fminf(nz, 1.f - 1e-7f)) / nz;
  float4 o;
  o.x = cc * z.x; o.y = cc * z.y; o.z = cc * z.z; o.w = cc * z.w;
  return o;
}

// -------- velocity t=0: 4 waves per row, pairs split across waves.
__global__ __launch_bounds__(256) void vel_feat_t0_k(
    const float* __restrict__ Z, unsigned short* __restrict__ Fh,
    float* __restrict__ VSUM)
{
  __shared__ float red[4][256];
  const int r = blockIdx.x;
  const int wave = threadIdx.x >> 6, lane = threadIdx.x & 63;
  const float* zr = Z + (size_t)r * 38 * 256;

  float4 vs = make_float4(0.f, 0.f, 0.f, 0.f);
  for (int j = wave; j < 29; j += 4) {
    float4 p = pair_log(zr, j, lane);
    vs.x += p.x; vs.y += p.y; vs.z += p.z; vs.w += p.w;
  }
  *reinterpret_cast<float4*>(&red[wave][lane * 4]) = vs;
  __syncthreads();

  const size_t fb = (size_t)r * 768 + lane * 4;
  if (wave == 0) {
    float4 a0 = *reinterpret_cast<const float4*>(&red[0][lane * 4]);
    float4 a1 = *reinterpret_cast<const float4*>(&red[1][lane * 4]);
    float4 a2 = *reinterpret_cast<const float4*>(&red[2][lane * 4]);
    float4 a3 = *reinterpret_cast<const float4*>(&red[3][lane * 4]);
    vs.x = a0.x + a1.x + a2.x + a3.x;
    vs.y = a0.y + a1.y + a2.y + a3.y;
    vs.z = a0.z + a1.z + a2.z + a3.z;
    vs.w = a0.w + a1.w + a2.w + a3.w;
    *reinterpret_cast<float4*>(VSUM + (size_t)r * 256 + lane * 4) = vs;
    const float s29 = 1.f / 29.f;
    float4 o;
    o.x = vs.x * s29; o.y = vs.y * s29; o.z = vs.z * s29; o.w = vs.w * s29;
    store_hi4(Fh, fb + 512, o);
  } else if (wave == 1) {
    float4 fl = logmap0_col(zr, 29, lane);   // z_last
    store_hi4(Fh, fb, fl);
  } else if (wave == 2) {
    float4 fp = logmap0_col(zr, 28, lane);   // z_prev
    store_hi4(Fh, fb + 256, fp);
  }
}

// --------- fused: z_next = expmap(z_last, sum VP + b3); writes
// U[r*8+t] = logmap0(z_next) (stage-C fusion); then (if t<7) incremental
// velocity + FEAT for step t+1. 2 waves per row (role 0 main, 1 helper).
__global__ __launch_bounds__(256) void expmap_vel_fused_k(
    float* __restrict__ Z, const float* __restrict__ VP,
    const float* __restrict__ b3, unsigned short* __restrict__ Fh,
    float* __restrict__ VSUM, unsigned short* __restrict__ Uh, int t)
{
  __shared__ float pmL[2][256];
  const int wave = threadIdx.x >> 6, lane = threadIdx.x & 63;
  const int rloc = wave >> 1;            // 0..1
  const int role = wave & 1;             // 0 main, 1 helper
  const int r = blockIdx.x * 2 + rloc;
  float* zr = Z + (size_t)r * 38 * 256;
  const size_t fb = (size_t)r * 768 + lane * 4;

  float4 res, u;
  float coef = 0.f, rn = 0.f, x2 = 0.f;

  if (role == 0) {
    float4 x = *reinterpret_cast<const float4*>(zr + (size_t)(t + 29) * 256 + lane * 4);
    float4 v = *reinterpret_cast<const float4*>(b3 + lane * 4);
#pragma unroll
    for (int p = 0; p < 4; ++p) {
      float4 a = *reinterpret_cast<const float4*>(
          VP + (size_t)p * 655360u + (size_t)r * 256 + lane * 4);
      v.x += a.x; v.y += a.y; v.z += a.z; v.w += a.w;
    }
    x2 = wave_sum(x.x * x.x + x.y * x.y + x.z * x.z + x.w * x.w);
    float v2 = wave_sum(v.x * v.x + v.y * v.y + v.z * v.z + v.w * v.w);
    float xv = wave_sum(x.x * v.x + x.y * v.y + x.z * v.z + x.w * v.w);

    float vn = fmaxf(sqrtf(v2), EPS_F);
    float lamx = 2.f / fmaxf(1.f - x2, EPS_F);
    float s = tanhf(0.5f * lamx * vn) / vn;
    float xy = s * xv;
    float y2 = s * s * v2;
    float a  = 1.f + 2.f * xy + y2;
    float bb = 1.f - x2;
    float den = fmaxf(1.f + 2.f * xy + x2 * y2, EPS_F);
    float inv = 1.f / den;
    res.x = (a * x.x + bb * s * v.x) * inv;
    res.y = (a * x.y + bb * s * v.y) * inv;
    res.z = (a * x.z + bb * s * v.z) * inv;
    res.w = (a * x.w + bb * s * v.w) * inv;
    float r2 = wave_sum(res.x * res.x + res.y * res.y + res.z * res.z + res.w * res.w);
    rn = sqrtf(r2);
    if (rn > MAX_NORM_F) {
      float sc = MAX_NORM_F / fmaxf(rn, EPS_F);
      res.x *= sc; res.y *= sc; res.z *= sc; res.w *= sc;
      r2 = MAX_NORM_F * MAX_NORM_F;
      rn = MAX_NORM_F;
    }
    *reinterpret_cast<float4*>(zr + (size_t)(t + 30) * 256 + lane * 4) = res;

    // stage-C fusion: U[r*8 + t] = logmap0(z_next) = cl * res
    {
      float rnp = fmaxf(rn, EPS_F);
      float cl = atanhf(fminf(rnp, 1.f - 1e-7f)) / rnp;
      float4 o;
      o.x = cl * res.x; o.y = cl * res.y; o.z = cl * res.z; o.w = cl * res.w;
      store_hi4(Uh, ((size_t)(r * 8 + t)) * 256 + lane * 4, o);
      if (t < 7) store_hi4(Fh, fb, o);   // FEAT z_last column (same value)
    }

    if (t < 7) {
      float xyn = wave_sum(x.x * res.x + x.y * res.y + x.z * res.z + x.w * res.w);
      float an  = 1.f - 2.f * xyn + r2;
      float bbn = 1.f - x2;
      float denn = fmaxf(1.f - 2.f * xyn + x2 * r2, EPS_F);
      float invn = 1.f / denn;
      u.x = (bbn * res.x - an * x.x) * invn;
      u.y = (bbn * res.y - an * x.y) * invn;
      u.z = (bbn * res.z - an * x.z) * invn;
      u.w = (bbn * res.w - an * x.w) * invn;
      float u2 = wave_sum(u.x * u.x + u.y * u.y + u.z * u.z + u.w * u.w);
      float un = fmaxf(sqrtf(u2), EPS_F);
      coef = fmaxf(1.f - x2, EPS_F) * atanhf(fminf(un, 1.f - 1e-7f)) / un;
    }
  } else if (t < 7) {
    // helper: pm (independent of res) + cp-FEAT column
    float4 pm = pair_log(zr, t, lane);
    *reinterpret_cast<float4*>(&pmL[rloc][lane * 4]) = pm;
    float4 x = *reinterpret_cast<const float4*>(zr + (size_t)(t + 29) * 256 + lane * 4);
    float hx2 = wave_sum(x.x * x.x + x.y * x.y + x.z * x.z + x.w * x.w);
    float nx = fmaxf(sqrtf(hx2), EPS_F);
    float cp = atanhf(fminf(nx, 1.f - 1e-7f)) / nx;
    float4 o;
    o.x = cp * x.x; o.y = cp * x.y; o.z = cp * x.z; o.w = cp * x.w;
    store_hi4(Fh, fb + 256, o);
  }

  __syncthreads();

  if (role == 0 && t < 7) {
    float4 pm = *reinterpret_cast<const float4*>(&pmL[rloc][lane * 4]);
    float4 vs = *reinterpret_cast<const float4*>(VSUM + (size_t)r * 256 + lane * 4);
    vs.x += coef * u.x - pm.x; vs.y += coef * u.y - pm.y;
    vs.z += coef * u.z - pm.z; vs.w += coef * u.w - pm.w;
    *reinterpret_cast<float4*>(VSUM + (size_t)r * 256 + lane * 4) = vs;

    const float s29 = 1.f / 29.f;
    float4 o;
    o.x = vs.x * s29; o.y = vs.y * s29; o.z = vs.z * s29; o.w = vs.w * s29;
    store_hi4(Fh, fb + 512, o);
  }
}

// ---------------------------------------------------------------- launcher
extern "C" void kernel_launch(void* const* d_in, const int* in_sizes, int n_in,
                              void* d_out, int out_size, void* d_ws, size_t ws_size,
                              hipStream_t stream)
{
  const float* c0 = (const float*)d_in[0];
  const float* c1 = (const float*)d_in[1];
  const float* c2 = (const float*)d_in[2];
  const float* c3 = (const float*)d_in[3];
  const float* W_embed = (const float*)d_in[4];
  const float* b_embed = (const float*)d_in[5];
  const float* ln_g    = (const float*)d_in[6];
  const float* ln_b    = (const float*)d_in[7];
  const float* W1 = (const float*)d_in[8];
  const float* b1 = (const float*)d_in[9];
  const float* W2 = (const float*)d_in[10];
  const float* b2 = (const float*)d_in[11];
  const float* W3 = (const float*)d_in[12];
  const float* b3 = (const float*)d_in[13];
  const float* W_out = (const float*)d_in[14];
  const float* b_out = (const float*)d_in[15];
  float* out = (float*)d_out;
  float* ws  = (float*)d_ws;

  // ---- ws layout (proven footprint).
  float* Z = ws;
  unsigned short* Abf = (unsigned short*)ws;        // aliases Z (stage A only)
  unsigned short* Rs = (unsigned short*)(ws + 24903680u);
  unsigned short* TAN = Rs + 20000000u;             // 4*15360*256 shorts
  unsigned short* W1h = Rs;                         // [1024][768]
  unsigned short* W1l = Rs + 786432u;
  unsigned short* W2h = Rs + 1572864u;              // [1024][1024]
  unsigned short* W2l = Rs + 2621440u;
  unsigned short* W3h = Rs + 3670016u;              // [256][1024]
  unsigned short* W3l = Rs + 3932160u;
  unsigned short* Woh = Rs + 4194304u;              // [504][256]
  unsigned short* Wol = Rs + 4323328u;
  unsigned short* FEATh = Rs + 4452352u;            // [2560][768]
  unsigned short* H1h = Rs + 6418432u;              // [2560][1024]
  unsigned short* H2h = Rs + 9039872u;              // [2560][1024]
  unsigned short* Uh  = Rs + 11661312u;             // [20480][256]
  float* VP   = ws + 34338816u;                     // 4 x 2560*256 parts
  float* VSUM = ws + 39581696u;                     // 2560*256

  unsigned short* EW = (unsigned short*)d_out;      // embed weights scratch

  dim3 blk(256);

  // Stage A: fused pre-pass (c2bf + all 8 weight splits) -> embed GEMM -> LN
  {
    WS8 d;
    for (int c = 0; c < 4; ++c) {
      d.W[c] = W_embed + (size_t)c * 504 * 256;
      d.Th[c] = EW + (size_t)c * 262144u;
      d.Tl[c] = EW + (size_t)c * 262144u + 131072u;
      d.K[c] = 504; d.N[c] = 256; d.Kp[c] = 512;
    }
    d.W[4] = W1;    d.Th[4] = W1h; d.Tl[4] = W1l; d.K[4] = 768;  d.N[4] = 1024; d.Kp[4] = 768;
    d.W[5] = W2;    d.Th[5] = W2h; d.Tl[5] = W2l; d.K[5] = 1024; d.N[5] = 1024; d.Kp[5] = 1024;
    d.W[6] = W3;    d.Th[6] = W3h; d.Tl[6] = W3l; d.K[6] = 1024; d.N[6] = 256;  d.Kp[6] = 1024;
    d.W[7] = W_out; d.Th[7] = Woh; d.Tl[7] = Wol; d.K[7] = 256;  d.N[7] = 504;  d.Kp[7] = 256;
    prep_k<<<dim3(15360 + 2048), blk, 0, stream>>>(d, c0, c1, c2, c3, Abf);
  }
  gemm_embed1<<<dim3(480, 2), blk, 0, stream>>>(Abf, EW, b_embed, TAN);
  ln_expmap0_k<<<dim3(3840), blk, 0, stream>>>(TAN, ln_g, ln_b, Z);

  // Stage B: 8 recurrent steps (x1 weights; vel/feat + U-write fused)
  vel_feat_t0_k<<<dim3(2560), blk, 0, stream>>>(Z, FEATh, VSUM);
  for (int t = 0; t < 8; ++t) {
    gemm_n64_x1<<<dim3(20, 16, 1), blk, 0, stream>>>(
        FEATh, 768, W1h, 768, b1, nullptr, H1h,
        1024, 2560, 1024, 768, 768, 1);
    gemm_n64_x1<<<dim3(20, 16, 1), blk, 0, stream>>>(
        H1h, 1024, W2h, 1024, b2, nullptr, H2h,
        1024, 2560, 1024, 1024, 1024, 1);
    gemm_n64_x1<<<dim3(20, 4, 4), blk, 0, stream>>>(
        H2h, 1024, W3h, 1024, nullptr, VP, nullptr,
        256, 2560, 256, 1024, 256, 0);
    expmap_vel_fused_k<<<dim3(1280), blk, 0, stream>>>(
        Z, VP, b3, FEATh, VSUM, Uh, t);
  }

  // Stage C: final projection into d_out (U written by step loop)
  gemm_n64_x1<<<dim3(160, 8, 1), blk, 0, stream>>>(
      Uh, 256, Woh, 256, b_out, out, nullptr,
      504, 20480, 504, 256, 256, 0);
}